// Round 11
// baseline (138.662 us; speedup 1.0000x reference)
//
#include <hip/hip_runtime.h>
#include <hip/hip_bf16.h>

#define S_LEN 2048
#define E_DIM 512
#define D_DIM 64
#define H_NUM 8
#define B_NUM 2
#define BH_NUM 16
#define NQA 257
#define QAE_W 512                 // clamp-extended QA row width
#define KSPLIT 4
#define KV_PER (S_LEN / KSPLIT)   // 512 keys per block
#define NT (KV_PER / 64)          // 8 tiles
#define QTILE 256                 // q-rows per block (8 waves x 32)
#define BNDW 112                  // band width (covers 102-wide span)

typedef _Float16 half8 __attribute__((ext_vector_type(8)));
typedef float f32x16 __attribute__((ext_vector_type(16)));
typedef unsigned int uint2v __attribute__((ext_vector_type(2)));
typedef unsigned int uint4v __attribute__((ext_vector_type(4)));

static __device__ __forceinline__ f32x16 MFMA(half8 a, half8 b, f32x16 c) {
    return __builtin_amdgcn_mfma_f32_32x32x16_f16(a, b, c, 0, 0, 0);
}
static __device__ __forceinline__ f32x16 ZERO16() {
    f32x16 z;
    #pragma unroll
    for (int i = 0; i < 16; ++i) z[i] = 0.f;
    return z;
}
static __device__ __forceinline__ unsigned int PKRTZ(float a, float b) {
    return __builtin_bit_cast(unsigned int, __builtin_amdgcn_cvt_pkrtz(a, b));
}

// ---------------------------------------------------------------------------
// cast xs (fp32) -> Xh (fp16)
// ---------------------------------------------------------------------------
__global__ __launch_bounds__(256) void cast_x_kernel(
    const float* __restrict__ xs, _Float16* __restrict__ Xh)
{
    const int idx = (blockIdx.x * 256 + threadIdx.x) * 8;
    float4 a = *(const float4*)&xs[idx];
    float4 b = *(const float4*)&xs[idx + 4];
    half8 o;
    o[0] = (_Float16)a.x; o[1] = (_Float16)a.y; o[2] = (_Float16)a.z; o[3] = (_Float16)a.w;
    o[4] = (_Float16)b.x; o[5] = (_Float16)b.y; o[6] = (_Float16)b.z; o[7] = (_Float16)b.w;
    *(half8*)&Xh[idx] = o;
}

// ---------------------------------------------------------------------------
// cast + transpose weights -> Wht[type][h][n=64][k=512] fp16  (z = 0,1,2)
// z == 3: cast a_k -> fp16 (first 9 (y*8+x) blocks)
// ---------------------------------------------------------------------------
__global__ __launch_bounds__(256) void cast_wak_kernel(
    const float* __restrict__ w_q, const float* __restrict__ w_k,
    const float* __restrict__ w_v, const float* __restrict__ w_o,
    const float* __restrict__ a_k,
    _Float16* __restrict__ Wht, _Float16* __restrict__ akh)
{
    __shared__ float T[64][68];
    const int type = blockIdx.z;
    const int t = threadIdx.x;
    if (type == 3) {
        const int bn = blockIdx.y * 8 + blockIdx.x;
        if (bn >= 9) return;
        const int idx = (bn * 256 + t) * 8;
        if (idx < NQA * 64) {
            float4 a = *(const float4*)&a_k[idx];
            float4 b = *(const float4*)&a_k[idx + 4];
            half8 o;
            o[0] = (_Float16)a.x; o[1] = (_Float16)a.y; o[2] = (_Float16)a.z; o[3] = (_Float16)a.w;
            o[4] = (_Float16)b.x; o[5] = (_Float16)b.y; o[6] = (_Float16)b.z; o[7] = (_Float16)b.w;
            *(half8*)&akh[idx] = o;
        }
        return;
    }
    const int kt = blockIdx.x, h = blockIdx.y;
    const float* W = (type == 0) ? w_q : (type == 1) ? w_k : w_v;
    const float scale = (type == 0) ? 0.125f : (type == 2 ? w_o[h] : 1.0f);
    const int kr = t >> 2, nseg = (t & 3) * 16;
    #pragma unroll
    for (int i = 0; i < 4; ++i)
        *(float4*)&T[kr][nseg + 4 * i] =
            *(const float4*)&W[((size_t)h * 512 + kt * 64 + kr) * 64 + nseg + 4 * i];
    __syncthreads();
    const int nr = t >> 2, kseg = (t & 3) * 16;
    _Float16* dst = Wht + ((size_t)(type * 8 + h) * 64 + nr) * 512 + kt * 64 + kseg;
    #pragma unroll
    for (int i = 0; i < 2; ++i) {
        half8 o;
        #pragma unroll
        for (int j = 0; j < 8; ++j) o[j] = (_Float16)(T[kseg + 8 * i + j][nr] * scale);
        *(half8*)&dst[8 * i] = o;
    }
}

// ---------------------------------------------------------------------------
// MFMA projections: out[2048x64] = Xh[b] * Wht[type][h]^T   (K=512)
// grid (16 mtiles, 16 bh, 3 type), block 256 (4 waves x 32 rows)
// ---------------------------------------------------------------------------
__global__ __launch_bounds__(256) void proj_mfma_kernel(
    const _Float16* __restrict__ Xh, const _Float16* __restrict__ Wht,
    _Float16* __restrict__ Qh, _Float16* __restrict__ Kh,
    _Float16* __restrict__ Vt)
{
    __shared__ _Float16 Xlds[2][128][72];
    __shared__ _Float16 Wlds[2][64][72];

    const int mt = blockIdx.x, bh = blockIdx.y, type = blockIdx.z;
    const int b = bh >> 3, h = bh & 7;
    const int m0 = mt * 128;
    const int t = threadIdx.x, wid = t >> 6, lane = t & 63;
    const int lq = lane & 31, lh = lane >> 5;

    const _Float16* W = Wht + (size_t)(type * 8 + h) * 64 * 512;
    const _Float16* X = Xh + ((size_t)b * S_LEN + m0) * 512;

    const int xrow = t >> 1, xseg = (t & 1) * 32;
    const int wrow = t >> 2, wseg = (t & 3) * 16;

    #pragma unroll
    for (int i = 0; i < 4; ++i)
        *(half8*)&Xlds[0][xrow][xseg + 8 * i] =
            *(const half8*)&X[(size_t)xrow * 512 + xseg + 8 * i];
    #pragma unroll
    for (int i = 0; i < 2; ++i)
        *(half8*)&Wlds[0][wrow][wseg + 8 * i] =
            *(const half8*)&W[(size_t)wrow * 512 + wseg + 8 * i];
    __syncthreads();

    f32x16 acc[2];
    acc[0] = ZERO16(); acc[1] = ZERO16();
    int cur = 0;
    for (int c = 0; c < 8; ++c) {
        half8 xst[4], wst[2];
        if (c < 7) {
            const int k0 = (c + 1) * 64;
            #pragma unroll
            for (int i = 0; i < 4; ++i)
                xst[i] = *(const half8*)&X[(size_t)xrow * 512 + k0 + xseg + 8 * i];
            #pragma unroll
            for (int i = 0; i < 2; ++i)
                wst[i] = *(const half8*)&W[(size_t)wrow * 512 + k0 + wseg + 8 * i];
        }
        #pragma unroll
        for (int kc = 0; kc < 4; ++kc) {
            half8 a  = *(const half8*)&Xlds[cur][wid * 32 + lq][kc * 16 + lh * 8];
            half8 b0 = *(const half8*)&Wlds[cur][lq][kc * 16 + lh * 8];
            half8 b1 = *(const half8*)&Wlds[cur][32 + lq][kc * 16 + lh * 8];
            acc[0] = MFMA(a, b0, acc[0]);
            acc[1] = MFMA(a, b1, acc[1]);
        }
        if (c < 7) {
            #pragma unroll
            for (int i = 0; i < 4; ++i)
                *(half8*)&Xlds[cur ^ 1][xrow][xseg + 8 * i] = xst[i];
            #pragma unroll
            for (int i = 0; i < 2; ++i)
                *(half8*)&Wlds[cur ^ 1][wrow][wseg + 8 * i] = wst[i];
        }
        __syncthreads();
        cur ^= 1;
    }

    _Float16* ob = &Wlds[0][0][0];
    #pragma unroll
    for (int n = 0; n < 2; ++n)
        #pragma unroll
        for (int r = 0; r < 16; ++r) {
            int row = wid * 32 + (r & 3) + ((r >> 2) << 3) + (lh << 2);
            ob[row * 72 + n * 32 + lq] = (_Float16)acc[n][r];
        }
    __syncthreads();

    if (type == 2) {
        const int v = t >> 2, sseg = (t & 3) * 32;
        _Float16* dst = Vt + ((size_t)bh * 64 + v) * S_LEN + m0 + sseg;
        #pragma unroll
        for (int i = 0; i < 4; ++i) {
            half8 o;
            #pragma unroll
            for (int j = 0; j < 8; ++j) o[j] = ob[(sseg + 8 * i + j) * 72 + v];
            *(half8*)&dst[8 * i] = o;
        }
    } else {
        _Float16* P = (type == 0) ? Qh : Kh;
        const int row = t >> 1, seg = (t & 1) * 32;
        _Float16* dst = P + ((size_t)bh * S_LEN + m0 + row) * 64 + seg;
        #pragma unroll
        for (int i = 0; i < 4; ++i)
            *(half8*)&dst[8 * i] = *(const half8*)&ob[row * 72 + seg + 8 * i];
    }
}

// ---------------------------------------------------------------------------
// MFMA QA -> clamp-extended table, INCLUDING padding:
//   core: QAe[bh][s][idx+128] = Q[s].ak[idx], idx in [0,256]
//   pad:  cols [0,128) <- idx0 value; cols [384,512) <- idx256 value
// ---------------------------------------------------------------------------
__global__ __launch_bounds__(256) void qa_mfma_kernel(
    const _Float16* __restrict__ Qh, const _Float16* __restrict__ akh,
    _Float16* __restrict__ QAe)
{
    __shared__ _Float16 ak[288][72];
    __shared__ _Float16 SLo[128], SHi[128];
    const int m0 = blockIdx.x * 128, bh = blockIdx.y;
    const int t = threadIdx.x, wid = t >> 6, lane = t & 63;
    const int lq = lane & 31, lh = lane >> 5;

    for (int r = t; r < 288; r += 256) {
        if (r < NQA) {
            #pragma unroll
            for (int i = 0; i < 8; ++i)
                *(half8*)&ak[r][8 * i] = *(const half8*)&akh[(size_t)r * 64 + 8 * i];
        } else {
            half8 z = {};
            #pragma unroll
            for (int i = 0; i < 8; ++i) *(half8*)&ak[r][8 * i] = z;
        }
    }
    __syncthreads();

    const int qg = m0 + wid * 32 + lq;
    half8 qfr[4];
    #pragma unroll
    for (int kc = 0; kc < 4; ++kc)
        qfr[kc] = *(const half8*)&Qh[((size_t)bh * S_LEN + qg) * 64 + kc * 16 + lh * 8];

    for (int nsub = 0; nsub < 9; ++nsub) {
        f32x16 acc = ZERO16();
        #pragma unroll
        for (int kc = 0; kc < 4; ++kc) {
            half8 bf = *(const half8*)&ak[nsub * 32 + lq][kc * 16 + lh * 8];
            acc = MFMA(qfr[kc], bf, acc);
        }
        const int col = nsub * 32 + lq;
        if (col < NQA) {
            #pragma unroll
            for (int r = 0; r < 16; ++r) {
                const int row = m0 + wid * 32 + (r & 3) + ((r >> 2) << 3) + (lh << 2);
                const _Float16 v = (_Float16)acc[r];
                QAe[((size_t)bh * S_LEN + row) * QAE_W + col + 128] = v;
                if (col == 0)   SLo[row - m0] = v;
                if (col == 256) SHi[row - m0] = v;
            }
        }
    }
    __syncthreads();

    const int prow = t >> 1, pseg = (t & 1) * 64;
    const _Float16 lo = SLo[prow], hi = SHi[prow];
    half8 vlo, vhi;
    #pragma unroll
    for (int j = 0; j < 8; ++j) { vlo[j] = lo; vhi[j] = hi; }
    _Float16* pb = QAe + ((size_t)bh * S_LEN + m0 + prow) * QAE_W;
    #pragma unroll
    for (int i = 0; i < 8; ++i) {
        *(half8*)&pb[pseg + 8 * i] = vlo;          // cols 0..127
        *(half8*)&pb[384 + pseg + 8 * i] = vhi;    // cols 384..511
    }
}

// ---------------------------------------------------------------------------
// Flash attention, 512-thread blocks (8 waves x 32 q-rows = 256 q-rows),
// KSPLIT=4, grid = 512 blocks (2/CU!, XCD-swizzled). Single-buffered K/V
// (write-from-regs -> barrier -> compute; regs prefetched 2 tiles ahead).
// LDS 75.8KB/block -> 2 blocks/CU -> 4 waves/SIMD: one block's barrier
// waits are hidden by the other block's compute.
// ---------------------------------------------------------------------------
__global__ __launch_bounds__(512, 4) void attn_kernel(
    const _Float16* __restrict__ Qh, const _Float16* __restrict__ Kh,
    const _Float16* __restrict__ Vt, const _Float16* __restrict__ QAe,
    _Float16* __restrict__ Po, float2* __restrict__ Ml)
{
    __shared__ __align__(16) _Float16 Klds[64][72];                    //  9,216 B
    __shared__ __align__(16) _Float16 Vlds[64][72];                    //  9,216 B
    __shared__ __align__(16) _Float16 Bnd[8][32][BNDW];                // 57,344 B
    _Float16* Obuf = &Bnd[0][0][0];                                    // [256][72] overlay

    const int p0 = blockIdx.x;                 // 0..511
    const int nb = (p0 & 7) * 64 + (p0 >> 3);  // XCD swizzle: 2 bh per XCD
    const int bh = nb >> 5;
    const int rem = nb & 31;
    const int qt = rem & 7, ks = rem >> 3;
    const int i0 = qt * QTILE, k0 = ks * KV_PER;

    const int t = threadIdx.x, wid = t >> 6, lane = t & 63;
    const int lq = lane & 31, lh = lane >> 5;
    const int i0w = i0 + wid * 32;             // this wave's 32 q-rows
    const int qg = i0w + lq;

    // block-uniform bias mode: 1 = all pairs clip at +128, 2 = all at -128
    int mode = 0;
    if (k0 >= i0 + QTILE - 1 + 128) mode = 1;
    else if (k0 + KV_PER - 1 <= i0 - 128) mode = 2;

    half8 qf[4];
    #pragma unroll
    for (int kc = 0; kc < 4; ++kc)
        qf[kc] = *(const half8*)&Qh[((size_t)bh * S_LEN + qg) * 64 + kc * 16 + lh * 8];

    const _Float16* qaeRow = QAe + ((size_t)bh * S_LEN + qg) * QAE_W;
    const float qa_lo = (float)qaeRow[128];   // idx 0
    const float qa_hi = (float)qaeRow[384];   // idx 256
    const _Float16* BndSrc = QAe + ((size_t)bh * S_LEN + i0w) * QAE_W;

    float rm = -1e30f, rl = 0.f;
    f32x16 acco[2];
    acco[0] = ZERO16(); acco[1] = ZERO16();

    // K/V staging: 512 threads, each 16B of K-tile and 16B of Vt-tile
    const int srow = t >> 3, sseg = (t & 7) * 8;
    const _Float16* Kbase = Kh + ((size_t)bh * S_LEN + k0) * 64;
    const _Float16* Vbase = Vt + ((size_t)bh * 64 + srow) * S_LEN + k0;

    // band staging: lane pair per row; 7 x 16B per lane
    const int brow = lane >> 1;                // 0..31
    const int bhalf = (lane & 1) * 56;         // halves offset (112B, 16B-aligned)

    half8 kA, vA, kB, vB, breg[7];
    kA = *(const half8*)&Kbase[(size_t)srow * 64 + sseg];
    vA = *(const half8*)&Vbase[sseg];
    kB = *(const half8*)&Kbase[(size_t)(64 + srow) * 64 + sseg];
    vB = *(const half8*)&Vbase[64 + sseg];

    // band prefetch for tile 0
    bool inb_next;
    {
        const int d0 = k0 - i0w;
        inb_next = (mode == 0) && (d0 < 159) && (d0 > -191);
        if (inb_next) {
            const int cw0n = (d0 + 225) & ~7;
            #pragma unroll
            for (int i = 0; i < 7; ++i)
                breg[i] = *(const half8*)&BndSrc[(size_t)brow * QAE_W + cw0n + bhalf + i * 8];
        }
    }

    #pragma unroll
    for (int jt = 0; jt < NT; ++jt) {
        if (jt) __syncthreads();               // all waves done reading prev tile
        *(half8*)&Klds[srow][sseg] = kA;
        *(half8*)&Vlds[srow][sseg] = vA;
        kA = kB; vA = vB;
        if (jt + 2 < NT) {                     // issue loads 2 tiles ahead
            const int jg = (jt + 2) * 64;
            kB = *(const half8*)&Kbase[(size_t)(jg + srow) * 64 + sseg];
            vB = *(const half8*)&Vbase[jg + sseg];
        }

        const int diff = k0 + jt * 64 - i0w;
        const bool inband = inb_next;
        const int cw0 = (diff + 225) & ~7;     // 16B-aligned band start (c')

        // write this tile's (prefetched) band regs -> per-wave LDS
        if (inband) {
            #pragma unroll
            for (int i = 0; i < 7; ++i)
                *(half8*)&Bnd[wid][brow][bhalf + i * 8] = breg[i];
        }
        // prefetch next tile's band
        {
            const int dn = diff + 64;
            inb_next = (jt + 1 < NT) && (mode == 0) && (dn < 159) && (dn > -191);
            if (inb_next) {
                const int cw0n = (dn + 225) & ~7;
                #pragma unroll
                for (int i = 0; i < 7; ++i)
                    breg[i] = *(const half8*)&BndSrc[(size_t)brow * QAE_W + cw0n + bhalf + i * 8];
            }
        }
        __syncthreads();                       // K/V writes visible

        // S^T = K . Q^T
        f32x16 accs[2];
        accs[0] = ZERO16(); accs[1] = ZERO16();
        __builtin_amdgcn_s_setprio(1);
        #pragma unroll
        for (int kc = 0; kc < 4; ++kc) {
            half8 ka = *(const half8*)&Klds[lq][kc * 16 + lh * 8];
            half8 kb = *(const half8*)&Klds[32 + lq][kc * 16 + lh * 8];
            accs[0] = MFMA(ka, qf[kc], accs[0]);
            accs[1] = MFMA(kb, qf[kc], accs[1]);
        }
        __builtin_amdgcn_s_setprio(0);

        const bool allhi = (mode == 1) || (mode == 0 && diff >= 159);
        const bool alllo = (mode == 2) || (mode == 0 && diff <= -191);
        float bunif = 0.f;
        if (allhi) bunif = qa_hi;
        else if (alllo) bunif = qa_lo;
        else {
            asm volatile("s_waitcnt lgkmcnt(0)" ::: "memory");
            __builtin_amdgcn_sched_barrier(0);
            const int pb = diff + 256 - cw0 - lq;   // + keyoff in [0,102]
            #pragma unroll
            for (int m = 0; m < 2; ++m)
                #pragma unroll
                for (int r = 0; r < 16; ++r) {
                    const int keyoff = m * 32 + (r & 3) + ((r >> 2) << 3) + (lh << 2);
                    accs[m][r] += (float)Bnd[wid][lq][pb + keyoff];
                }
        }

        // online softmax: tree max, shift-folded uniform bias
        float t8[8];
        #pragma unroll
        for (int i = 0; i < 8; ++i)
            t8[i] = fmaxf(fmaxf(accs[0][i], accs[0][i + 8]),
                          fmaxf(accs[1][i], accs[1][i + 8]));
        float tmax = fmaxf(fmaxf(fmaxf(t8[0], t8[1]), fmaxf(t8[2], t8[3])),
                           fmaxf(fmaxf(t8[4], t8[5]), fmaxf(t8[6], t8[7])));
        tmax = fmaxf(tmax, __shfl_xor(tmax, 32));
        const float mnew = fmaxf(rm, tmax + bunif);
        const bool resc = __any(mnew > rm);
        const float corr = __expf(rm - mnew);
        const float shift = mnew - bunif;
        rm = mnew;

        #pragma unroll
        for (int m = 0; m < 2; ++m)
            #pragma unroll
            for (int r = 0; r < 16; ++r)
                accs[m][r] = __expf(accs[m][r] - shift);

        float s8[8];
        #pragma unroll
        for (int i = 0; i < 8; ++i)
            s8[i] = (accs[0][i] + accs[0][i + 8]) + (accs[1][i] + accs[1][i + 8]);
        float psum = ((s8[0] + s8[1]) + (s8[2] + s8[3])) +
                     ((s8[4] + s8[5]) + (s8[6] + s8[7]));
        psum += __shfl_xor(psum, 32);

        if (resc) {
            rl = rl * corr + psum;
            #pragma unroll
            for (int n = 0; n < 2; ++n)
                #pragma unroll
                for (int r = 0; r < 16; ++r) acco[n][r] *= corr;
        } else {
            rl += psum;
        }

        // pack P -> PV B-fragments in-register (cvt_pkrtz + permlane32_swap)
        half8 pf[4];
        #pragma unroll
        for (int kc = 0; kc < 4; ++kc) {
            const int m = kc >> 1, rb = (kc & 1) * 8;
            unsigned int a01 = PKRTZ(accs[m][rb + 0], accs[m][rb + 1]);
            unsigned int a45 = PKRTZ(accs[m][rb + 4], accs[m][rb + 5]);
            unsigned int a23 = PKRTZ(accs[m][rb + 2], accs[m][rb + 3]);
            unsigned int a67 = PKRTZ(accs[m][rb + 6], accs[m][rb + 7]);
            uint2v r02 = __builtin_amdgcn_permlane32_swap(a01, a45, false, false);
            uint2v r13 = __builtin_amdgcn_permlane32_swap(a23, a67, false, false);
            uint4v wv;
            wv[0] = r02[0]; wv[1] = r13[0]; wv[2] = r02[1]; wv[3] = r13[1];
            pf[kc] = __builtin_bit_cast(half8, wv);
        }

        // O^T += V^T . P^T
        __builtin_amdgcn_s_setprio(1);
        #pragma unroll
        for (int kc = 0; kc < 4; ++kc) {
            half8 v0 = *(const half8*)&Vlds[lq][kc * 16 + lh * 8];
            half8 v1 = *(const half8*)&Vlds[32 + lq][kc * 16 + lh * 8];
            acco[0] = MFMA(v0, pf[kc], acco[0]);
            acco[1] = MFMA(v1, pf[kc], acco[1]);
        }
        __builtin_amdgcn_s_setprio(0);
    }

    // epilogue: all waves done -> overlay O-buffer on Bnd
    __syncthreads();
    const int orow = wid * 32 + lq;
    #pragma unroll
    for (int n = 0; n < 2; ++n)
        #pragma unroll
        for (int rq = 0; rq < 4; ++rq) {
            uint2v hv;
            hv[0] = PKRTZ(acco[n][rq * 4 + 0], acco[n][rq * 4 + 1]);
            hv[1] = PKRTZ(acco[n][rq * 4 + 2], acco[n][rq * 4 + 3]);
            *(uint2v*)&Obuf[(size_t)orow * 72 + n * 32 + rq * 8 + lh * 4] = hv;
        }
    if (lh == 0)
        Ml[((size_t)ks * BH_NUM + bh) * S_LEN + qg] = make_float2(rm, rl);
    asm volatile("s_waitcnt lgkmcnt(0)" ::: "memory");
    __builtin_amdgcn_sched_barrier(0);
    const int rrow = wid * 32 + (lane >> 1);
    const int rseg = (lane & 1) * 32;
    _Float16* dst = Po + (((size_t)ks * BH_NUM + bh) * S_LEN + i0 + rrow) * 64 + rseg;
    #pragma unroll
    for (int i = 0; i < 4; ++i)
        *(half8*)&dst[8 * i] = *(const half8*)&Obuf[(size_t)rrow * 72 + rseg + 8 * i];
}

// ---------------------------------------------------------------------------
// merge partials + combine heads:
// out[b][s][v] = sum_h (sum_p e^{m_p-M} O_p) / (sum_p e^{m_p-M} l_p)
// ---------------------------------------------------------------------------
__global__ __launch_bounds__(256) void merge_kernel(
    const _Float16* __restrict__ Po, const float2* __restrict__ Ml,
    float* __restrict__ out)
{
    const int b = blockIdx.y;
    const int s = blockIdx.x * 32 + (threadIdx.x >> 3);
    const int v0 = (threadIdx.x & 7) * 8;
    float acc[8] = {0, 0, 0, 0, 0, 0, 0, 0};
    #pragma unroll
    for (int h = 0; h < 8; ++h) {
        const int bh = b * 8 + h;
        float m[KSPLIT], l[KSPLIT];
        #pragma unroll
        for (int p = 0; p < KSPLIT; ++p) {
            const float2 v = Ml[((size_t)p * BH_NUM + bh) * S_LEN + s];
            m[p] = v.x; l[p] = v.y;
        }
        float M = fmaxf(fmaxf(m[0], m[1]), fmaxf(m[2], m[3]));
        float L = 0.f, w[KSPLIT];
        #pragma unroll
        for (int p = 0; p < KSPLIT; ++p) { w[p] = __expf(m[p] - M); L += w[p] * l[p]; }
        const float invL = 1.0f / L;
        #pragma unroll
        for (int p = 0; p < KSPLIT; ++p) {
            half8 o = *(const half8*)&Po[(((size_t)p * BH_NUM + bh) * S_LEN + s) * 64 + v0];
            const float wp = w[p] * invL;
            #pragma unroll
            for (int j = 0; j < 8; ++j) acc[j] += wp * (float)o[j];
        }
    }
    float4 o0 = {acc[0], acc[1], acc[2], acc[3]};
    float4 o1 = {acc[4], acc[5], acc[6], acc[7]};
    *(float4*)&out[((size_t)b * S_LEN + s) * 64 + v0] = o0;
    *(float4*)&out[((size_t)b * S_LEN + s) * 64 + v0 + 4] = o1;
}

// ---------------------------------------------------------------------------
extern "C" void kernel_launch(void* const* d_in, const int* in_sizes, int n_in,
                              void* d_out, int out_size, void* d_ws, size_t ws_size,
                              hipStream_t stream)
{
    const float* xs  = (const float*)d_in[0];
    const float* w_q = (const float*)d_in[1];
    const float* w_k = (const float*)d_in[2];
    const float* w_v = (const float*)d_in[3];
    const float* w_o = (const float*)d_in[4];
    const float* a_k = (const float*)d_in[5];
    float* out = (float*)d_out;

    char* w = (char*)d_ws;
    _Float16* Xh  = (_Float16*)w;  w += (size_t)B_NUM * S_LEN * E_DIM * 2;        // 4 MB
    _Float16* Wht = (_Float16*)w;  w += (size_t)3 * H_NUM * 64 * 512 * 2;         // 1.5 MB
    _Float16* akh = (_Float16*)w;  w += 33024;
    _Float16* Qh  = (_Float16*)w;  w += (size_t)BH_NUM * S_LEN * 64 * 2;
    _Float16* Kh  = (_Float16*)w;  w += (size_t)BH_NUM * S_LEN * 64 * 2;
    _Float16* Vt  = (_Float16*)w;  w += (size_t)BH_NUM * S_LEN * 64 * 2;
    _Float16* QAe = (_Float16*)w;  w += (size_t)BH_NUM * S_LEN * QAE_W * 2;       // 33.5 MB
    _Float16* Po  = (_Float16*)w;  w += (size_t)KSPLIT * BH_NUM * S_LEN * 64 * 2; // 16.8 MB
    float2*   Ml  = (float2*)w;                                                    // 1 MB

    cast_x_kernel<<<1024, 256, 0, stream>>>(xs, Xh);
    cast_wak_kernel<<<dim3(8, 8, 4), 256, 0, stream>>>(w_q, w_k, w_v, w_o, a_k, Wht, akh);
    proj_mfma_kernel<<<dim3(16, 16, 3), 256, 0, stream>>>(Xh, Wht, Qh, Kh, Vt);
    qa_mfma_kernel<<<dim3(16, 16), 256, 0, stream>>>(Qh, akh, QAe);
    attn_kernel<<<512, 512, 0, stream>>>(Qh, Kh, Vt, QAe, Po, Ml);
    merge_kernel<<<dim3(64, 2), 256, 0, stream>>>(Po, Ml, out);
}

// Round 12
// 90.629 us; speedup vs baseline: 1.5300x; 1.5300x over previous
//
#include <hip/hip_runtime.h>
#include <hip/hip_bf16.h>

#define S_LEN 2048
#define E_DIM 512
#define D_DIM 64
#define H_NUM 8
#define B_NUM 2
#define BH_NUM 16
#define NQA 257
#define QAE_W 512                 // clamp-extended QA row width
#define KSPLIT 2
#define KV_PER (S_LEN / KSPLIT)   // 1024 keys per block
#define NT (KV_PER / 64)          // 16 tiles
#define QTILE 128                 // q-rows per block (4 waves x 32)
#define BNDW 112                  // band width (covers 102-wide span)

typedef _Float16 half8 __attribute__((ext_vector_type(8)));
typedef float f32x16 __attribute__((ext_vector_type(16)));
typedef unsigned int uint2v __attribute__((ext_vector_type(2)));
typedef unsigned int uint4v __attribute__((ext_vector_type(4)));

static __device__ __forceinline__ f32x16 MFMA(half8 a, half8 b, f32x16 c) {
    return __builtin_amdgcn_mfma_f32_32x32x16_f16(a, b, c, 0, 0, 0);
}
static __device__ __forceinline__ f32x16 ZERO16() {
    f32x16 z;
    #pragma unroll
    for (int i = 0; i < 16; ++i) z[i] = 0.f;
    return z;
}
static __device__ __forceinline__ unsigned int PKRTZ(float a, float b) {
    return __builtin_bit_cast(unsigned int, __builtin_amdgcn_cvt_pkrtz(a, b));
}

// ---------------------------------------------------------------------------
// cast xs (fp32) -> Xh (fp16)
// ---------------------------------------------------------------------------
__global__ __launch_bounds__(256) void cast_x_kernel(
    const float* __restrict__ xs, _Float16* __restrict__ Xh)
{
    const int idx = (blockIdx.x * 256 + threadIdx.x) * 8;
    float4 a = *(const float4*)&xs[idx];
    float4 b = *(const float4*)&xs[idx + 4];
    half8 o;
    o[0] = (_Float16)a.x; o[1] = (_Float16)a.y; o[2] = (_Float16)a.z; o[3] = (_Float16)a.w;
    o[4] = (_Float16)b.x; o[5] = (_Float16)b.y; o[6] = (_Float16)b.z; o[7] = (_Float16)b.w;
    *(half8*)&Xh[idx] = o;
}

// ---------------------------------------------------------------------------
// cast + transpose weights -> Wht[type][h][n=64][k=512] fp16  (z = 0,1,2)
// z == 3: cast a_k -> fp16 (first 9 (y*8+x) blocks)
// ---------------------------------------------------------------------------
__global__ __launch_bounds__(256) void cast_wak_kernel(
    const float* __restrict__ w_q, const float* __restrict__ w_k,
    const float* __restrict__ w_v, const float* __restrict__ w_o,
    const float* __restrict__ a_k,
    _Float16* __restrict__ Wht, _Float16* __restrict__ akh)
{
    __shared__ float T[64][68];
    const int type = blockIdx.z;
    const int t = threadIdx.x;
    if (type == 3) {
        const int bn = blockIdx.y * 8 + blockIdx.x;
        if (bn >= 9) return;
        const int idx = (bn * 256 + t) * 8;
        if (idx < NQA * 64) {
            float4 a = *(const float4*)&a_k[idx];
            float4 b = *(const float4*)&a_k[idx + 4];
            half8 o;
            o[0] = (_Float16)a.x; o[1] = (_Float16)a.y; o[2] = (_Float16)a.z; o[3] = (_Float16)a.w;
            o[4] = (_Float16)b.x; o[5] = (_Float16)b.y; o[6] = (_Float16)b.z; o[7] = (_Float16)b.w;
            *(half8*)&akh[idx] = o;
        }
        return;
    }
    const int kt = blockIdx.x, h = blockIdx.y;
    const float* W = (type == 0) ? w_q : (type == 1) ? w_k : w_v;
    const float scale = (type == 0) ? 0.125f : (type == 2 ? w_o[h] : 1.0f);
    const int kr = t >> 2, nseg = (t & 3) * 16;
    #pragma unroll
    for (int i = 0; i < 4; ++i)
        *(float4*)&T[kr][nseg + 4 * i] =
            *(const float4*)&W[((size_t)h * 512 + kt * 64 + kr) * 64 + nseg + 4 * i];
    __syncthreads();
    const int nr = t >> 2, kseg = (t & 3) * 16;
    _Float16* dst = Wht + ((size_t)(type * 8 + h) * 64 + nr) * 512 + kt * 64 + kseg;
    #pragma unroll
    for (int i = 0; i < 2; ++i) {
        half8 o;
        #pragma unroll
        for (int j = 0; j < 8; ++j) o[j] = (_Float16)(T[kseg + 8 * i + j][nr] * scale);
        *(half8*)&dst[8 * i] = o;
    }
}

// ---------------------------------------------------------------------------
// MFMA projections + fused QA (type 0).
// Phase A: out[128x64] = Xh[b](128 rows) * Wht[type][h]^T (K=512)
// Phase B (type==0 only): QAe[bh][row][idx+128] = Q[row].ak[idx] + padding,
// reusing the Q-tile already in LDS (ob) -- saves the qa kernel + re-reads.
// grid (16 mtiles, 16 bh, 3 type), block 256 (4 waves x 32 rows)
// ---------------------------------------------------------------------------
__global__ __launch_bounds__(256) void proj_mfma_kernel(
    const _Float16* __restrict__ Xh, const _Float16* __restrict__ Wht,
    const _Float16* __restrict__ akh,
    _Float16* __restrict__ Qh, _Float16* __restrict__ Kh,
    _Float16* __restrict__ Vt, _Float16* __restrict__ QAe)
{
    __shared__ __align__(16) _Float16 raw[30208];   // 60416 B
    _Float16 (*Xlds)[128][72] = (_Float16(*)[128][72])raw;          // phase A
    _Float16 (*Wlds)[64][72]  = (_Float16(*)[64][72])(raw + 18432); // phase A
    _Float16* ob  = raw;                                            // [128][72] B
    _Float16 (*ak)[72] = (_Float16(*)[72])(raw + 9216);             // [288][72] B
    _Float16* SLo = raw + 29952;                                    // [128]
    _Float16* SHi = raw + 30080;                                    // [128]

    const int mt = blockIdx.x, bh = blockIdx.y, type = blockIdx.z;
    const int b = bh >> 3, h = bh & 7;
    const int m0 = mt * 128;
    const int t = threadIdx.x, wid = t >> 6, lane = t & 63;
    const int lq = lane & 31, lh = lane >> 5;

    const _Float16* W = Wht + (size_t)(type * 8 + h) * 64 * 512;
    const _Float16* X = Xh + ((size_t)b * S_LEN + m0) * 512;

    const int xrow = t >> 1, xseg = (t & 1) * 32;
    const int wrow = t >> 2, wseg = (t & 3) * 16;

    #pragma unroll
    for (int i = 0; i < 4; ++i)
        *(half8*)&Xlds[0][xrow][xseg + 8 * i] =
            *(const half8*)&X[(size_t)xrow * 512 + xseg + 8 * i];
    #pragma unroll
    for (int i = 0; i < 2; ++i)
        *(half8*)&Wlds[0][wrow][wseg + 8 * i] =
            *(const half8*)&W[(size_t)wrow * 512 + wseg + 8 * i];
    __syncthreads();

    f32x16 acc[2];
    acc[0] = ZERO16(); acc[1] = ZERO16();
    int cur = 0;
    for (int c = 0; c < 8; ++c) {
        half8 xst[4], wst[2];
        if (c < 7) {
            const int k0 = (c + 1) * 64;
            #pragma unroll
            for (int i = 0; i < 4; ++i)
                xst[i] = *(const half8*)&X[(size_t)xrow * 512 + k0 + xseg + 8 * i];
            #pragma unroll
            for (int i = 0; i < 2; ++i)
                wst[i] = *(const half8*)&W[(size_t)wrow * 512 + k0 + wseg + 8 * i];
        }
        #pragma unroll
        for (int kc = 0; kc < 4; ++kc) {
            half8 a  = *(const half8*)&Xlds[cur][wid * 32 + lq][kc * 16 + lh * 8];
            half8 b0 = *(const half8*)&Wlds[cur][lq][kc * 16 + lh * 8];
            half8 b1 = *(const half8*)&Wlds[cur][32 + lq][kc * 16 + lh * 8];
            acc[0] = MFMA(a, b0, acc[0]);
            acc[1] = MFMA(a, b1, acc[1]);
        }
        if (c < 7) {
            #pragma unroll
            for (int i = 0; i < 4; ++i)
                *(half8*)&Xlds[cur ^ 1][xrow][xseg + 8 * i] = xst[i];
            #pragma unroll
            for (int i = 0; i < 2; ++i)
                *(half8*)&Wlds[cur ^ 1][wrow][wseg + 8 * i] = wst[i];
        }
        __syncthreads();
        cur ^= 1;
    }

    // epilogue: acc -> ob (raw[0..9216), former Xlds[0] area -- main loop done)
    #pragma unroll
    for (int n = 0; n < 2; ++n)
        #pragma unroll
        for (int r = 0; r < 16; ++r) {
            int row = wid * 32 + (r & 3) + ((r >> 2) << 3) + (lh << 2);
            ob[row * 72 + n * 32 + lq] = (_Float16)acc[n][r];
        }
    __syncthreads();

    if (type == 2) {
        const int v = t >> 2, sseg = (t & 3) * 32;
        _Float16* dst = Vt + ((size_t)bh * 64 + v) * S_LEN + m0 + sseg;
        #pragma unroll
        for (int i = 0; i < 4; ++i) {
            half8 o;
            #pragma unroll
            for (int j = 0; j < 8; ++j) o[j] = ob[(sseg + 8 * i + j) * 72 + v];
            *(half8*)&dst[8 * i] = o;
        }
        return;
    }

    {   // Qh / Kh store
        _Float16* P = (type == 0) ? Qh : Kh;
        const int row = t >> 1, seg = (t & 1) * 32;
        _Float16* dst = P + ((size_t)bh * S_LEN + m0 + row) * 64 + seg;
        #pragma unroll
        for (int i = 0; i < 4; ++i)
            *(half8*)&dst[8 * i] = *(const half8*)&ob[row * 72 + seg + 8 * i];
    }
    if (type != 0) return;

    // -------- phase B: fused QA (Q-tile already in ob) --------
    for (int r = t; r < 288; r += 256) {
        if (r < NQA) {
            #pragma unroll
            for (int i = 0; i < 8; ++i)
                *(half8*)&ak[r][8 * i] = *(const half8*)&akh[(size_t)r * 64 + 8 * i];
        } else {
            half8 z = {};
            #pragma unroll
            for (int i = 0; i < 8; ++i) *(half8*)&ak[r][8 * i] = z;
        }
    }
    __syncthreads();

    half8 qfr[4];
    #pragma unroll
    for (int kc = 0; kc < 4; ++kc)
        qfr[kc] = *(const half8*)&ob[(wid * 32 + lq) * 72 + kc * 16 + lh * 8];

    for (int nsub = 0; nsub < 9; ++nsub) {
        f32x16 qa = ZERO16();
        #pragma unroll
        for (int kc = 0; kc < 4; ++kc) {
            half8 bf = *(const half8*)&ak[nsub * 32 + lq][kc * 16 + lh * 8];
            qa = MFMA(qfr[kc], bf, qa);
        }
        const int col = nsub * 32 + lq;
        if (col < NQA) {
            #pragma unroll
            for (int r = 0; r < 16; ++r) {
                const int row = m0 + wid * 32 + (r & 3) + ((r >> 2) << 3) + (lh << 2);
                const _Float16 v = (_Float16)qa[r];
                QAe[((size_t)bh * S_LEN + row) * QAE_W + col + 128] = v;
                if (col == 0)   SLo[row - m0] = v;
                if (col == 256) SHi[row - m0] = v;
            }
        }
    }
    __syncthreads();

    const int prow = t >> 1, pseg = (t & 1) * 64;
    const _Float16 lo = SLo[prow], hi = SHi[prow];
    half8 vlo, vhi;
    #pragma unroll
    for (int j = 0; j < 8; ++j) { vlo[j] = lo; vhi[j] = hi; }
    _Float16* pb = QAe + ((size_t)bh * S_LEN + m0 + prow) * QAE_W;
    #pragma unroll
    for (int i = 0; i < 8; ++i) {
        *(half8*)&pb[pseg + 8 * i] = vlo;          // cols 0..127
        *(half8*)&pb[384 + pseg + 8 * i] = vhi;    // cols 384..511
    }
}

// ---------------------------------------------------------------------------
// Flash attention, 256-thread blocks (4 waves x 32 q-rows = 128 q-rows),
// KSPLIT=2, grid = 16 bh x 16 qt x 2 ks = 512 blocks -> 2 blocks/CU:
// TWO INDEPENDENT barrier groups per CU hide each other's stalls.
// Double-buffered K/V (1 barrier/tile) + per-wave bias band prefetched
// 1 tile ahead. LDS = 64KB exactly. Natural VGPR (no launch-bounds squeeze).
// ---------------------------------------------------------------------------
__global__ __launch_bounds__(256) void attn_kernel(
    const _Float16* __restrict__ Qh, const _Float16* __restrict__ Kh,
    const _Float16* __restrict__ Vt, const _Float16* __restrict__ QAe,
    _Float16* __restrict__ Po, float2* __restrict__ Ml)
{
    __shared__ __align__(16) _Float16 Klds[2][64][72];                 // 18432 B
    __shared__ __align__(16) _Float16 Vlds[2][64][72];                 // 18432 B
    __shared__ __align__(16) _Float16 Bnd[4][32][BNDW];                // 28672 B
    _Float16* Obuf = &Bnd[0][0][0];                                    // [128][72] overlay

    const int p0 = blockIdx.x;                 // 0..511
    const int nb = (p0 & 7) * 64 + (p0 >> 3);  // XCD swizzle: 2 bh per XCD
    const int bh = nb >> 5;
    const int rem = nb & 31;
    const int qt = rem & 15, ks = rem >> 4;
    const int i0 = qt * QTILE, k0 = ks * KV_PER;

    const int t = threadIdx.x, wid = t >> 6, lane = t & 63;
    const int lq = lane & 31, lh = lane >> 5;
    const int i0w = i0 + wid * 32;             // this wave's 32 q-rows
    const int qg = i0w + lq;

    // block-uniform bias mode: 1 = all pairs clip at +128, 2 = all at -128
    int mode = 0;
    if (k0 >= i0 + QTILE - 1 + 128) mode = 1;
    else if (k0 + KV_PER - 1 <= i0 - 128) mode = 2;

    half8 qf[4];
    #pragma unroll
    for (int kc = 0; kc < 4; ++kc)
        qf[kc] = *(const half8*)&Qh[((size_t)bh * S_LEN + qg) * 64 + kc * 16 + lh * 8];

    const _Float16* qaeRow = QAe + ((size_t)bh * S_LEN + qg) * QAE_W;
    const float qa_lo = (float)qaeRow[128];   // idx 0
    const float qa_hi = (float)qaeRow[384];   // idx 256
    const _Float16* BndSrc = QAe + ((size_t)bh * S_LEN + i0w) * QAE_W;

    float rm = -1e30f, rl = 0.f;
    f32x16 acco[2];
    acco[0] = ZERO16(); acco[1] = ZERO16();

    // K/V staging: 256 threads, each 32B of K-tile and 32B of Vt-tile
    const int srow = t >> 2, sseg = (t & 3) * 16;
    const _Float16* Kbase = Kh + ((size_t)bh * S_LEN + k0) * 64;
    const _Float16* Vbase = Vt + ((size_t)bh * 64 + srow) * S_LEN + k0;

    // band staging: lane pair per row; 7 x 16B per lane
    const int brow = lane >> 1;                // 0..31
    const int bhalf = (lane & 1) * 56;         // 112-wide split in two 56 halves

    half8 kst0, kst1, vst0, vst1, breg[7];
    *(half8*)&Klds[0][srow][sseg]     = *(const half8*)&Kbase[(size_t)srow * 64 + sseg];
    *(half8*)&Klds[0][srow][sseg + 8] = *(const half8*)&Kbase[(size_t)srow * 64 + sseg + 8];
    *(half8*)&Vlds[0][srow][sseg]     = *(const half8*)&Vbase[sseg];
    *(half8*)&Vlds[0][srow][sseg + 8] = *(const half8*)&Vbase[sseg + 8];
    kst0 = *(const half8*)&Kbase[(size_t)(64 + srow) * 64 + sseg];
    kst1 = *(const half8*)&Kbase[(size_t)(64 + srow) * 64 + sseg + 8];
    vst0 = *(const half8*)&Vbase[64 + sseg];
    vst1 = *(const half8*)&Vbase[64 + sseg + 8];

    // band prefetch for tile 0
    bool inb_next;
    {
        const int d0 = k0 - i0w;
        inb_next = (mode == 0) && (d0 < 159) && (d0 > -191);
        if (inb_next) {
            const int cw0n = (d0 + 225) & ~7;
            #pragma unroll
            for (int i = 0; i < 7; ++i)
                breg[i] = *(const half8*)&BndSrc[(size_t)brow * QAE_W + cw0n + bhalf + i * 8];
        }
    }
    __syncthreads();

    for (int jt = 0; jt < NT; ++jt) {
        const int cur = jt & 1;
        if (jt) __syncthreads();
        if (jt + 1 < NT) {                      // stage tile jt+1 -> other buf
            *(half8*)&Klds[cur ^ 1][srow][sseg]     = kst0;
            *(half8*)&Klds[cur ^ 1][srow][sseg + 8] = kst1;
            *(half8*)&Vlds[cur ^ 1][srow][sseg]     = vst0;
            *(half8*)&Vlds[cur ^ 1][srow][sseg + 8] = vst1;
        }
        if (jt + 2 < NT) {                      // issue loads 2 tiles ahead
            const int jg = (jt + 2) * 64;
            kst0 = *(const half8*)&Kbase[(size_t)(jg + srow) * 64 + sseg];
            kst1 = *(const half8*)&Kbase[(size_t)(jg + srow) * 64 + sseg + 8];
            vst0 = *(const half8*)&Vbase[jg + sseg];
            vst1 = *(const half8*)&Vbase[jg + sseg + 8];
        }

        const int diff = k0 + jt * 64 - i0w;
        const bool inband = inb_next;
        const int cw0 = (diff + 225) & ~7;     // 16B-aligned band start (c')

        // write this tile's (prefetched) band regs -> per-wave LDS
        if (inband) {
            #pragma unroll
            for (int i = 0; i < 7; ++i)
                *(half8*)&Bnd[wid][brow][bhalf + i * 8] = breg[i];
        }
        // prefetch next tile's band
        {
            const int dn = diff + 64;
            inb_next = (jt + 1 < NT) && (mode == 0) && (dn < 159) && (dn > -191);
            if (inb_next) {
                const int cw0n = (dn + 225) & ~7;
                #pragma unroll
                for (int i = 0; i < 7; ++i)
                    breg[i] = *(const half8*)&BndSrc[(size_t)brow * QAE_W + cw0n + bhalf + i * 8];
            }
        }

        // S^T = K . Q^T
        f32x16 accs[2];
        accs[0] = ZERO16(); accs[1] = ZERO16();
        __builtin_amdgcn_s_setprio(1);
        #pragma unroll
        for (int kc = 0; kc < 4; ++kc) {
            half8 ka = *(const half8*)&Klds[cur][lq][kc * 16 + lh * 8];
            half8 kb = *(const half8*)&Klds[cur][32 + lq][kc * 16 + lh * 8];
            accs[0] = MFMA(ka, qf[kc], accs[0]);
            accs[1] = MFMA(kb, qf[kc], accs[1]);
        }
        __builtin_amdgcn_s_setprio(0);

        const bool allhi = (mode == 1) || (mode == 0 && diff >= 159);
        const bool alllo = (mode == 2) || (mode == 0 && diff <= -191);
        float bunif = 0.f;
        if (allhi) bunif = qa_hi;
        else if (alllo) bunif = qa_lo;
        else {
            asm volatile("s_waitcnt lgkmcnt(0)" ::: "memory");
            __builtin_amdgcn_sched_barrier(0);
            const int pb = diff + 256 - cw0 - lq;   // + keyoff in [0,102]
            #pragma unroll
            for (int m = 0; m < 2; ++m)
                #pragma unroll
                for (int r = 0; r < 16; ++r) {
                    const int keyoff = m * 32 + (r & 3) + ((r >> 2) << 3) + (lh << 2);
                    accs[m][r] += (float)Bnd[wid][lq][pb + keyoff];
                }
        }

        // online softmax: tree max, shift-folded uniform bias
        float t8[8];
        #pragma unroll
        for (int i = 0; i < 8; ++i)
            t8[i] = fmaxf(fmaxf(accs[0][i], accs[0][i + 8]),
                          fmaxf(accs[1][i], accs[1][i + 8]));
        float tmax = fmaxf(fmaxf(fmaxf(t8[0], t8[1]), fmaxf(t8[2], t8[3])),
                           fmaxf(fmaxf(t8[4], t8[5]), fmaxf(t8[6], t8[7])));
        tmax = fmaxf(tmax, __shfl_xor(tmax, 32));
        const float mnew = fmaxf(rm, tmax + bunif);
        const bool resc = __any(mnew > rm);
        const float corr = __expf(rm - mnew);
        const float shift = mnew - bunif;
        rm = mnew;

        #pragma unroll
        for (int m = 0; m < 2; ++m)
            #pragma unroll
            for (int r = 0; r < 16; ++r)
                accs[m][r] = __expf(accs[m][r] - shift);

        float s8[8];
        #pragma unroll
        for (int i = 0; i < 8; ++i)
            s8[i] = (accs[0][i] + accs[0][i + 8]) + (accs[1][i] + accs[1][i + 8]);
        float psum = ((s8[0] + s8[1]) + (s8[2] + s8[3])) +
                     ((s8[4] + s8[5]) + (s8[6] + s8[7]));
        psum += __shfl_xor(psum, 32);

        if (resc) {
            rl = rl * corr + psum;
            #pragma unroll
            for (int n = 0; n < 2; ++n)
                #pragma unroll
                for (int r = 0; r < 16; ++r) acco[n][r] *= corr;
        } else {
            rl += psum;
        }

        // pack P -> PV B-fragments in-register (cvt_pkrtz + permlane32_swap)
        half8 pf[4];
        #pragma unroll
        for (int kc = 0; kc < 4; ++kc) {
            const int m = kc >> 1, rb = (kc & 1) * 8;
            unsigned int a01 = PKRTZ(accs[m][rb + 0], accs[m][rb + 1]);
            unsigned int a45 = PKRTZ(accs[m][rb + 4], accs[m][rb + 5]);
            unsigned int a23 = PKRTZ(accs[m][rb + 2], accs[m][rb + 3]);
            unsigned int a67 = PKRTZ(accs[m][rb + 6], accs[m][rb + 7]);
            uint2v r02 = __builtin_amdgcn_permlane32_swap(a01, a45, false, false);
            uint2v r13 = __builtin_amdgcn_permlane32_swap(a23, a67, false, false);
            uint4v wv;
            wv[0] = r02[0]; wv[1] = r13[0]; wv[2] = r02[1]; wv[3] = r13[1];
            pf[kc] = __builtin_bit_cast(half8, wv);
        }

        // O^T += V^T . P^T
        __builtin_amdgcn_s_setprio(1);
        #pragma unroll
        for (int kc = 0; kc < 4; ++kc) {
            half8 v0 = *(const half8*)&Vlds[cur][lq][kc * 16 + lh * 8];
            half8 v1 = *(const half8*)&Vlds[cur][32 + lq][kc * 16 + lh * 8];
            acco[0] = MFMA(v0, pf[kc], acco[0]);
            acco[1] = MFMA(v1, pf[kc], acco[1]);
        }
        __builtin_amdgcn_s_setprio(0);
    }

    // epilogue: all waves done -> overlay O-buffer on Bnd
    __syncthreads();
    const int orow = wid * 32 + lq;
    #pragma unroll
    for (int n = 0; n < 2; ++n)
        #pragma unroll
        for (int rq = 0; rq < 4; ++rq) {
            uint2v hv;
            hv[0] = PKRTZ(acco[n][rq * 4 + 0], acco[n][rq * 4 + 1]);
            hv[1] = PKRTZ(acco[n][rq * 4 + 2], acco[n][rq * 4 + 3]);
            *(uint2v*)&Obuf[(size_t)orow * 72 + n * 32 + rq * 8 + lh * 4] = hv;
        }
    if (lh == 0)
        Ml[((size_t)ks * BH_NUM + bh) * S_LEN + qg] = make_float2(rm, rl);
    asm volatile("s_waitcnt lgkmcnt(0)" ::: "memory");
    __builtin_amdgcn_sched_barrier(0);
    const int rrow = wid * 32 + (lane >> 1);
    const int rseg = (lane & 1) * 32;
    _Float16* dst = Po + (((size_t)ks * BH_NUM + bh) * S_LEN + i0 + rrow) * 64 + rseg;
    #pragma unroll
    for (int i = 0; i < 4; ++i)
        *(half8*)&dst[8 * i] = *(const half8*)&Obuf[(size_t)rrow * 72 + rseg + 8 * i];
}

// ---------------------------------------------------------------------------
// merge partials + combine heads:
// out[b][s][v] = sum_h (sum_p e^{m_p-M} O_p) / (sum_p e^{m_p-M} l_p)
// ---------------------------------------------------------------------------
__global__ __launch_bounds__(256) void merge_kernel(
    const _Float16* __restrict__ Po, const float2* __restrict__ Ml,
    float* __restrict__ out)
{
    const int b = blockIdx.y;
    const int s = blockIdx.x * 32 + (threadIdx.x >> 3);
    const int v0 = (threadIdx.x & 7) * 8;
    float acc[8] = {0, 0, 0, 0, 0, 0, 0, 0};
    #pragma unroll
    for (int h = 0; h < 8; ++h) {
        const int bh = b * 8 + h;
        float m[KSPLIT], l[KSPLIT];
        #pragma unroll
        for (int p = 0; p < KSPLIT; ++p) {
            const float2 v = Ml[((size_t)p * BH_NUM + bh) * S_LEN + s];
            m[p] = v.x; l[p] = v.y;
        }
        float M = fmaxf(m[0], m[1]);
        float L = 0.f, w[KSPLIT];
        #pragma unroll
        for (int p = 0; p < KSPLIT; ++p) { w[p] = __expf(m[p] - M); L += w[p] * l[p]; }
        const float invL = 1.0f / L;
        #pragma unroll
        for (int p = 0; p < KSPLIT; ++p) {
            half8 o = *(const half8*)&Po[(((size_t)p * BH_NUM + bh) * S_LEN + s) * 64 + v0];
            const float wp = w[p] * invL;
            #pragma unroll
            for (int j = 0; j < 8; ++j) acc[j] += wp * (float)o[j];
        }
    }
    float4 o0 = {acc[0], acc[1], acc[2], acc[3]};
    float4 o1 = {acc[4], acc[5], acc[6], acc[7]};
    *(float4*)&out[((size_t)b * S_LEN + s) * 64 + v0] = o0;
    *(float4*)&out[((size_t)b * S_LEN + s) * 64 + v0 + 4] = o1;
}

// ---------------------------------------------------------------------------
extern "C" void kernel_launch(void* const* d_in, const int* in_sizes, int n_in,
                              void* d_out, int out_size, void* d_ws, size_t ws_size,
                              hipStream_t stream)
{
    const float* xs  = (const float*)d_in[0];
    const float* w_q = (const float*)d_in[1];
    const float* w_k = (const float*)d_in[2];
    const float* w_v = (const float*)d_in[3];
    const float* w_o = (const float*)d_in[4];
    const float* a_k = (const float*)d_in[5];
    float* out = (float*)d_out;

    char* w = (char*)d_ws;
    _Float16* Xh  = (_Float16*)w;  w += (size_t)B_NUM * S_LEN * E_DIM * 2;        // 4 MB
    _Float16* Wht = (_Float16*)w;  w += (size_t)3 * H_NUM * 64 * 512 * 2;         // 1.5 MB
    _Float16* akh = (_Float16*)w;  w += 33024;
    _Float16* Qh  = (_Float16*)w;  w += (size_t)BH_NUM * S_LEN * 64 * 2;
    _Float16* Kh  = (_Float16*)w;  w += (size_t)BH_NUM * S_LEN * 64 * 2;
    _Float16* Vt  = (_Float16*)w;  w += (size_t)BH_NUM * S_LEN * 64 * 2;
    _Float16* QAe = (_Float16*)w;  w += (size_t)BH_NUM * S_LEN * QAE_W * 2;       // 33.5 MB
    _Float16* Po  = (_Float16*)w;  w += (size_t)KSPLIT * BH_NUM * S_LEN * 64 * 2; // 8.4 MB
    float2*   Ml  = (float2*)w;                                                    // 0.5 MB

    cast_x_kernel<<<1024, 256, 0, stream>>>(xs, Xh);
    cast_wak_kernel<<<dim3(8, 8, 4), 256, 0, stream>>>(w_q, w_k, w_v, w_o, a_k, Wht, akh);
    proj_mfma_kernel<<<dim3(16, 16, 3), 256, 0, stream>>>(Xh, Wht, akh, Qh, Kh, Vt, QAe);
    attn_kernel<<<512, 256, 0, stream>>>(Qh, Kh, Vt, QAe, Po, Ml);
    merge_kernel<<<dim3(64, 2), 256, 0, stream>>>(Po, Ml, out);
}

// Round 13
// 89.936 us; speedup vs baseline: 1.5418x; 1.0077x over previous
//
#include <hip/hip_runtime.h>
#include <hip/hip_bf16.h>

#define S_LEN 2048
#define E_DIM 512
#define D_DIM 64
#define H_NUM 8
#define B_NUM 2
#define BH_NUM 16
#define NQA 257
#define QAE_W 512                 // clamp-extended QA row width
#define KSPLIT 2
#define KV_PER (S_LEN / KSPLIT)   // 1024 keys per block
#define NT (KV_PER / 64)          // 16 tiles
#define QTILE 256                 // q-rows per attn block (8 waves x 32)

typedef _Float16 half8 __attribute__((ext_vector_type(8)));
typedef float f32x16 __attribute__((ext_vector_type(16)));
typedef unsigned int uint2v __attribute__((ext_vector_type(2)));
typedef unsigned int uint4v __attribute__((ext_vector_type(4)));

static __device__ __forceinline__ f32x16 MFMA(half8 a, half8 b, f32x16 c) {
    return __builtin_amdgcn_mfma_f32_32x32x16_f16(a, b, c, 0, 0, 0);
}
static __device__ __forceinline__ f32x16 ZERO16() {
    f32x16 z;
    #pragma unroll
    for (int i = 0; i < 16; ++i) z[i] = 0.f;
    return z;
}
static __device__ __forceinline__ unsigned int PKRTZ(float a, float b) {
    return __builtin_bit_cast(unsigned int, __builtin_amdgcn_cvt_pkrtz(a, b));
}

// ---------------------------------------------------------------------------
// cast xs (fp32) -> Xh (fp16)
// ---------------------------------------------------------------------------
__global__ __launch_bounds__(256) void cast_x_kernel(
    const float* __restrict__ xs, _Float16* __restrict__ Xh)
{
    const int idx = (blockIdx.x * 256 + threadIdx.x) * 8;
    float4 a = *(const float4*)&xs[idx];
    float4 b = *(const float4*)&xs[idx + 4];
    half8 o;
    o[0] = (_Float16)a.x; o[1] = (_Float16)a.y; o[2] = (_Float16)a.z; o[3] = (_Float16)a.w;
    o[4] = (_Float16)b.x; o[5] = (_Float16)b.y; o[6] = (_Float16)b.z; o[7] = (_Float16)b.w;
    *(half8*)&Xh[idx] = o;
}

// ---------------------------------------------------------------------------
// cast + transpose weights -> Wht[type][h][n=64][k=512] fp16  (z = 0,1,2)
// type 0 (w_q) scaled by log2(e)/8 so softmax can use raw exp2.
// z == 3: cast a_k -> fp16 (first 9 (y*8+x) blocks)
// ---------------------------------------------------------------------------
__global__ __launch_bounds__(256) void cast_wak_kernel(
    const float* __restrict__ w_q, const float* __restrict__ w_k,
    const float* __restrict__ w_v, const float* __restrict__ w_o,
    const float* __restrict__ a_k,
    _Float16* __restrict__ Wht, _Float16* __restrict__ akh)
{
    __shared__ float T[64][68];
    const int type = blockIdx.z;
    const int t = threadIdx.x;
    if (type == 3) {
        const int bn = blockIdx.y * 8 + blockIdx.x;
        if (bn >= 9) return;
        const int idx = (bn * 256 + t) * 8;
        if (idx < NQA * 64) {
            float4 a = *(const float4*)&a_k[idx];
            float4 b = *(const float4*)&a_k[idx + 4];
            half8 o;
            o[0] = (_Float16)a.x; o[1] = (_Float16)a.y; o[2] = (_Float16)a.z; o[3] = (_Float16)a.w;
            o[4] = (_Float16)b.x; o[5] = (_Float16)b.y; o[6] = (_Float16)b.z; o[7] = (_Float16)b.w;
            *(half8*)&akh[idx] = o;
        }
        return;
    }
    const int kt = blockIdx.x, h = blockIdx.y;
    const float* W = (type == 0) ? w_q : (type == 1) ? w_k : w_v;
    const float scale = (type == 0) ? 0.18033688011112042f   // log2(e)/8
                                    : (type == 2 ? w_o[h] : 1.0f);
    const int kr = t >> 2, nseg = (t & 3) * 16;
    #pragma unroll
    for (int i = 0; i < 4; ++i)
        *(float4*)&T[kr][nseg + 4 * i] =
            *(const float4*)&W[((size_t)h * 512 + kt * 64 + kr) * 64 + nseg + 4 * i];
    __syncthreads();
    const int nr = t >> 2, kseg = (t & 3) * 16;
    _Float16* dst = Wht + ((size_t)(type * 8 + h) * 64 + nr) * 512 + kt * 64 + kseg;
    #pragma unroll
    for (int i = 0; i < 2; ++i) {
        half8 o;
        #pragma unroll
        for (int j = 0; j < 8; ++j) o[j] = (_Float16)(T[kseg + 8 * i + j][nr] * scale);
        *(half8*)&dst[8 * i] = o;
    }
}

// ---------------------------------------------------------------------------
// MFMA projections + fused QA (type 0).
// Phase A: out[128x64] = Xh[b](128 rows) * Wht[type][h]^T (K=512)
// Phase B (type==0 only): QAe[bh][row][idx+128] = Q[row].ak[idx] + padding,
// reusing the Q-tile already in LDS.
// grid (16 mtiles, 16 bh, 3 type), block 256 (4 waves x 32 rows)
// ---------------------------------------------------------------------------
__global__ __launch_bounds__(256) void proj_mfma_kernel(
    const _Float16* __restrict__ Xh, const _Float16* __restrict__ Wht,
    const _Float16* __restrict__ akh,
    _Float16* __restrict__ Qh, _Float16* __restrict__ Kh,
    _Float16* __restrict__ Vt, _Float16* __restrict__ QAe)
{
    __shared__ __align__(16) _Float16 raw[30208];   // 60416 B
    _Float16 (*Xlds)[128][72] = (_Float16(*)[128][72])raw;          // phase A
    _Float16 (*Wlds)[64][72]  = (_Float16(*)[64][72])(raw + 18432); // phase A
    _Float16* ob  = raw;                                            // [128][72] B
    _Float16 (*ak)[72] = (_Float16(*)[72])(raw + 9216);             // [288][72] B
    _Float16* SLo = raw + 29952;                                    // [128]
    _Float16* SHi = raw + 30080;                                    // [128]

    const int mt = blockIdx.x, bh = blockIdx.y, type = blockIdx.z;
    const int b = bh >> 3, h = bh & 7;
    const int m0 = mt * 128;
    const int t = threadIdx.x, wid = t >> 6, lane = t & 63;
    const int lq = lane & 31, lh = lane >> 5;

    const _Float16* W = Wht + (size_t)(type * 8 + h) * 64 * 512;
    const _Float16* X = Xh + ((size_t)b * S_LEN + m0) * 512;

    const int xrow = t >> 1, xseg = (t & 1) * 32;
    const int wrow = t >> 2, wseg = (t & 3) * 16;

    #pragma unroll
    for (int i = 0; i < 4; ++i)
        *(half8*)&Xlds[0][xrow][xseg + 8 * i] =
            *(const half8*)&X[(size_t)xrow * 512 + xseg + 8 * i];
    #pragma unroll
    for (int i = 0; i < 2; ++i)
        *(half8*)&Wlds[0][wrow][wseg + 8 * i] =
            *(const half8*)&W[(size_t)wrow * 512 + wseg + 8 * i];
    __syncthreads();

    f32x16 acc[2];
    acc[0] = ZERO16(); acc[1] = ZERO16();
    int cur = 0;
    for (int c = 0; c < 8; ++c) {
        half8 xst[4], wst[2];
        if (c < 7) {
            const int k0 = (c + 1) * 64;
            #pragma unroll
            for (int i = 0; i < 4; ++i)
                xst[i] = *(const half8*)&X[(size_t)xrow * 512 + k0 + xseg + 8 * i];
            #pragma unroll
            for (int i = 0; i < 2; ++i)
                wst[i] = *(const half8*)&W[(size_t)wrow * 512 + k0 + wseg + 8 * i];
        }
        #pragma unroll
        for (int kc = 0; kc < 4; ++kc) {
            half8 a  = *(const half8*)&Xlds[cur][wid * 32 + lq][kc * 16 + lh * 8];
            half8 b0 = *(const half8*)&Wlds[cur][lq][kc * 16 + lh * 8];
            half8 b1 = *(const half8*)&Wlds[cur][32 + lq][kc * 16 + lh * 8];
            acc[0] = MFMA(a, b0, acc[0]);
            acc[1] = MFMA(a, b1, acc[1]);
        }
        if (c < 7) {
            #pragma unroll
            for (int i = 0; i < 4; ++i)
                *(half8*)&Xlds[cur ^ 1][xrow][xseg + 8 * i] = xst[i];
            #pragma unroll
            for (int i = 0; i < 2; ++i)
                *(half8*)&Wlds[cur ^ 1][wrow][wseg + 8 * i] = wst[i];
        }
        __syncthreads();
        cur ^= 1;
    }

    // epilogue: acc -> ob
    #pragma unroll
    for (int n = 0; n < 2; ++n)
        #pragma unroll
        for (int r = 0; r < 16; ++r) {
            int row = wid * 32 + (r & 3) + ((r >> 2) << 3) + (lh << 2);
            ob[row * 72 + n * 32 + lq] = (_Float16)acc[n][r];
        }
    __syncthreads();

    if (type == 2) {
        const int v = t >> 2, sseg = (t & 3) * 32;
        _Float16* dst = Vt + ((size_t)bh * 64 + v) * S_LEN + m0 + sseg;
        #pragma unroll
        for (int i = 0; i < 4; ++i) {
            half8 o;
            #pragma unroll
            for (int j = 0; j < 8; ++j) o[j] = ob[(sseg + 8 * i + j) * 72 + v];
            *(half8*)&dst[8 * i] = o;
        }
        return;
    }

    {   // Qh / Kh store
        _Float16* P = (type == 0) ? Qh : Kh;
        const int row = t >> 1, seg = (t & 1) * 32;
        _Float16* dst = P + ((size_t)bh * S_LEN + m0 + row) * 64 + seg;
        #pragma unroll
        for (int i = 0; i < 4; ++i)
            *(half8*)&dst[8 * i] = *(const half8*)&ob[row * 72 + seg + 8 * i];
    }
    if (type != 0) return;

    // -------- phase B: fused QA (Q-tile already in ob) --------
    for (int r = t; r < 288; r += 256) {
        if (r < NQA) {
            #pragma unroll
            for (int i = 0; i < 8; ++i)
                *(half8*)&ak[r][8 * i] = *(const half8*)&akh[(size_t)r * 64 + 8 * i];
        } else {
            half8 z = {};
            #pragma unroll
            for (int i = 0; i < 8; ++i) *(half8*)&ak[r][8 * i] = z;
        }
    }
    __syncthreads();

    half8 qfr[4];
    #pragma unroll
    for (int kc = 0; kc < 4; ++kc)
        qfr[kc] = *(const half8*)&ob[(wid * 32 + lq) * 72 + kc * 16 + lh * 8];

    for (int nsub = 0; nsub < 9; ++nsub) {
        f32x16 qa = ZERO16();
        #pragma unroll
        for (int kc = 0; kc < 4; ++kc) {
            half8 bf = *(const half8*)&ak[nsub * 32 + lq][kc * 16 + lh * 8];
            qa = MFMA(qfr[kc], bf, qa);
        }
        const int col = nsub * 32 + lq;
        if (col < NQA) {
            #pragma unroll
            for (int r = 0; r < 16; ++r) {
                const int row = m0 + wid * 32 + (r & 3) + ((r >> 2) << 3) + (lh << 2);
                const _Float16 v = (_Float16)qa[r];
                QAe[((size_t)bh * S_LEN + row) * QAE_W + col + 128] = v;
                if (col == 0)   SLo[row - m0] = v;
                if (col == 256) SHi[row - m0] = v;
            }
        }
    }
    __syncthreads();

    const int prow = t >> 1, pseg = (t & 1) * 64;
    const _Float16 lo = SLo[prow], hi = SHi[prow];
    half8 vlo, vhi;
    #pragma unroll
    for (int j = 0; j < 8; ++j) { vlo[j] = lo; vhi[j] = hi; }
    _Float16* pb = QAe + ((size_t)bh * S_LEN + m0 + prow) * QAE_W;
    #pragma unroll
    for (int i = 0; i < 8; ++i) {
        *(half8*)&pb[pseg + 8 * i] = vlo;          // cols 0..127
        *(half8*)&pb[384 + pseg + 8 * i] = vhi;    // cols 384..511
    }
}

// ---------------------------------------------------------------------------
// Flash attention (r10 config, best measured): 512-thread blocks (8 waves x
// 32 q-rows = 256 q-rows), KSPLIT=2, grid = 256 blocks (1/CU, XCD-swizzled).
// Double-buffered K/V + per-wave bias band prefetched 1 tile ahead.
// Softmax in exp2 domain (log2e folded into w_q scale).
// ---------------------------------------------------------------------------
__global__ __launch_bounds__(512) void attn_kernel(
    const _Float16* __restrict__ Qh, const _Float16* __restrict__ Kh,
    const _Float16* __restrict__ Vt, const _Float16* __restrict__ QAe,
    _Float16* __restrict__ Po, float2* __restrict__ Ml)
{
    __shared__ __align__(16) char smraw[36864];
    _Float16 (*Klds)[64][72] = (_Float16(*)[64][72])smraw;             // [2][64][72]
    _Float16 (*Vlds)[64][72] = (_Float16(*)[64][72])(smraw + 18432);   // [2][64][72]
    _Float16* Obuf = (_Float16*)smraw;                                 // [256][72]
    __shared__ __align__(16) _Float16 Bnd[8][32][128];                 // 64KB band

    const int p0 = blockIdx.x;                 // 0..255
    const int nb = (p0 & 7) * 32 + (p0 >> 3);  // XCD swizzle: 2 bh per XCD
    const int bh = nb >> 4;
    const int rem = nb & 15;
    const int qt = rem & 7, ks = rem >> 3;
    const int i0 = qt * QTILE, k0 = ks * KV_PER;

    const int t = threadIdx.x, wid = t >> 6, lane = t & 63;
    const int lq = lane & 31, lh = lane >> 5;
    const int i0w = i0 + wid * 32;             // this wave's 32 q-rows
    const int qg = i0w + lq;

    // block-uniform bias mode: 1 = all pairs clip at +128, 2 = all at -128
    int mode = 0;
    if (k0 >= i0 + QTILE - 1 + 128) mode = 1;
    else if (k0 + KV_PER - 1 <= i0 - 128) mode = 2;

    half8 qf[4];
    #pragma unroll
    for (int kc = 0; kc < 4; ++kc)
        qf[kc] = *(const half8*)&Qh[((size_t)bh * S_LEN + qg) * 64 + kc * 16 + lh * 8];

    const _Float16* qaeRow = QAe + ((size_t)bh * S_LEN + qg) * QAE_W;
    const float qa_lo = (float)qaeRow[128];   // idx 0
    const float qa_hi = (float)qaeRow[384];   // idx 256
    const _Float16* BndSrc = QAe + ((size_t)bh * S_LEN + i0w) * QAE_W;

    float rm = -1e30f, rl = 0.f;
    f32x16 acco[2];
    acco[0] = ZERO16(); acco[1] = ZERO16();

    // staging: 512 threads, each 16B of K-tile and 16B of Vt-tile per KV tile
    const int srow = t >> 3, sseg = (t & 7) * 8;
    const _Float16* Kbase = Kh + ((size_t)bh * S_LEN + k0) * 64;
    const _Float16* Vbase = Vt + ((size_t)bh * 64 + srow) * S_LEN + k0;

    const int brow = lane >> 4;                // 0..3 (band stage row group)
    const int bcol = (lane & 15) * 8;          // band stage col (halves)

    half8 kst, vst, breg[8];
    *(half8*)&Klds[0][srow][sseg] = *(const half8*)&Kbase[(size_t)srow * 64 + sseg];
    *(half8*)&Vlds[0][srow][sseg] = *(const half8*)&Vbase[sseg];
    kst = *(const half8*)&Kbase[(size_t)(64 + srow) * 64 + sseg];
    vst = *(const half8*)&Vbase[64 + sseg];

    // band prefetch for tile 0
    bool inb_next;
    {
        const int d0 = k0 - i0w;
        inb_next = (mode == 0) && (d0 < 159) && (d0 > -191);
        if (inb_next) {
            const int cw0n = (d0 + 225) & ~7;
            #pragma unroll
            for (int ps = 0; ps < 8; ++ps)
                breg[ps] = *(const half8*)&BndSrc[(size_t)(ps * 4 + brow) * QAE_W + cw0n + bcol];
        }
    }
    __syncthreads();

    for (int jt = 0; jt < NT; ++jt) {
        const int cur = jt & 1;
        if (jt) __syncthreads();
        if (jt + 1 < NT) {
            *(half8*)&Klds[cur ^ 1][srow][sseg] = kst;
            *(half8*)&Vlds[cur ^ 1][srow][sseg] = vst;
        }
        if (jt + 2 < NT) {
            const int jg = (jt + 2) * 64;
            kst = *(const half8*)&Kbase[(size_t)(jg + srow) * 64 + sseg];
            vst = *(const half8*)&Vbase[jg + sseg];
        }

        const int diff = k0 + jt * 64 - i0w;
        const bool inband = inb_next;
        const int cw0 = (diff + 225) & ~7;     // 16B-aligned band start (c')

        // write this tile's (prefetched) band regs -> per-wave LDS
        if (inband) {
            #pragma unroll
            for (int ps = 0; ps < 8; ++ps)
                *(half8*)&Bnd[wid][ps * 4 + brow][bcol] = breg[ps];
        }
        // prefetch next tile's band (latency hidden under this tile)
        {
            const int dn = diff + 64;
            inb_next = (jt + 1 < NT) && (mode == 0) && (dn < 159) && (dn > -191);
            if (inb_next) {
                const int cw0n = (dn + 225) & ~7;
                #pragma unroll
                for (int ps = 0; ps < 8; ++ps)
                    breg[ps] = *(const half8*)&BndSrc[(size_t)(ps * 4 + brow) * QAE_W + cw0n + bcol];
            }
        }

        // S^T = K . Q^T
        f32x16 accs[2];
        accs[0] = ZERO16(); accs[1] = ZERO16();
        __builtin_amdgcn_s_setprio(1);
        #pragma unroll
        for (int kc = 0; kc < 4; ++kc) {
            half8 ka = *(const half8*)&Klds[cur][lq][kc * 16 + lh * 8];
            half8 kb = *(const half8*)&Klds[cur][32 + lq][kc * 16 + lh * 8];
            accs[0] = MFMA(ka, qf[kc], accs[0]);
            accs[1] = MFMA(kb, qf[kc], accs[1]);
        }
        __builtin_amdgcn_s_setprio(0);

        const bool allhi = (mode == 1) || (mode == 0 && diff >= 159);
        const bool alllo = (mode == 2) || (mode == 0 && diff <= -191);
        float bunif = 0.f;
        if (allhi) bunif = qa_hi;
        else if (alllo) bunif = qa_lo;
        else {
            asm volatile("s_waitcnt lgkmcnt(0)" ::: "memory");
            __builtin_amdgcn_sched_barrier(0);
            const int pb = diff + 256 - cw0 - lq;   // + keyoff in [0,127]
            #pragma unroll
            for (int m = 0; m < 2; ++m)
                #pragma unroll
                for (int r = 0; r < 16; ++r) {
                    const int keyoff = m * 32 + (r & 3) + ((r >> 2) << 3) + (lh << 2);
                    accs[m][r] += (float)Bnd[wid][lq][pb + keyoff];
                }
        }

        // online softmax (exp2 domain): tree max, shift-folded uniform bias
        float t8[8];
        #pragma unroll
        for (int i = 0; i < 8; ++i)
            t8[i] = fmaxf(fmaxf(accs[0][i], accs[0][i + 8]),
                          fmaxf(accs[1][i], accs[1][i + 8]));
        float tmax = fmaxf(fmaxf(fmaxf(t8[0], t8[1]), fmaxf(t8[2], t8[3])),
                           fmaxf(fmaxf(t8[4], t8[5]), fmaxf(t8[6], t8[7])));
        tmax = fmaxf(tmax, __shfl_xor(tmax, 32));
        const float mnew = fmaxf(rm, tmax + bunif);
        const bool resc = __any(mnew > rm);
        const float corr = exp2f(rm - mnew);
        const float shift = mnew - bunif;
        rm = mnew;

        #pragma unroll
        for (int m = 0; m < 2; ++m)
            #pragma unroll
            for (int r = 0; r < 16; ++r)
                accs[m][r] = exp2f(accs[m][r] - shift);

        float s8[8];
        #pragma unroll
        for (int i = 0; i < 8; ++i)
            s8[i] = (accs[0][i] + accs[0][i + 8]) + (accs[1][i] + accs[1][i + 8]);
        float psum = ((s8[0] + s8[1]) + (s8[2] + s8[3])) +
                     ((s8[4] + s8[5]) + (s8[6] + s8[7]));
        psum += __shfl_xor(psum, 32);

        if (resc) {
            rl = rl * corr + psum;
            #pragma unroll
            for (int n = 0; n < 2; ++n)
                #pragma unroll
                for (int r = 0; r < 16; ++r) acco[n][r] *= corr;
        } else {
            rl += psum;
        }

        // pack P -> PV B-fragments in-register (cvt_pkrtz + permlane32_swap)
        half8 pf[4];
        #pragma unroll
        for (int kc = 0; kc < 4; ++kc) {
            const int m = kc >> 1, rb = (kc & 1) * 8;
            unsigned int a01 = PKRTZ(accs[m][rb + 0], accs[m][rb + 1]);
            unsigned int a45 = PKRTZ(accs[m][rb + 4], accs[m][rb + 5]);
            unsigned int a23 = PKRTZ(accs[m][rb + 2], accs[m][rb + 3]);
            unsigned int a67 = PKRTZ(accs[m][rb + 6], accs[m][rb + 7]);
            uint2v r02 = __builtin_amdgcn_permlane32_swap(a01, a45, false, false);
            uint2v r13 = __builtin_amdgcn_permlane32_swap(a23, a67, false, false);
            uint4v wv;
            wv[0] = r02[0]; wv[1] = r13[0]; wv[2] = r02[1]; wv[3] = r13[1];
            pf[kc] = __builtin_bit_cast(half8, wv);
        }

        // O^T += V^T . P^T
        __builtin_amdgcn_s_setprio(1);
        #pragma unroll
        for (int kc = 0; kc < 4; ++kc) {
            half8 v0 = *(const half8*)&Vlds[cur][lq][kc * 16 + lh * 8];
            half8 v1 = *(const half8*)&Vlds[cur][32 + lq][kc * 16 + lh * 8];
            acco[0] = MFMA(v0, pf[kc], acco[0]);
            acco[1] = MFMA(v1, pf[kc], acco[1]);
        }
        __builtin_amdgcn_s_setprio(0);
    }

    // epilogue: all waves done with K/V LDS -> overlay O-buffer
    __syncthreads();
    const int orow = wid * 32 + lq;
    #pragma unroll
    for (int n = 0; n < 2; ++n)
        #pragma unroll
        for (int rq = 0; rq < 4; ++rq) {
            uint2v hv;
            hv[0] = PKRTZ(acco[n][rq * 4 + 0], acco[n][rq * 4 + 1]);
            hv[1] = PKRTZ(acco[n][rq * 4 + 2], acco[n][rq * 4 + 3]);
            *(uint2v*)&Obuf[(size_t)orow * 72 + n * 32 + rq * 8 + lh * 4] = hv;
        }
    if (lh == 0)
        Ml[((size_t)ks * BH_NUM + bh) * S_LEN + qg] = make_float2(rm, rl);
    asm volatile("s_waitcnt lgkmcnt(0)" ::: "memory");
    __builtin_amdgcn_sched_barrier(0);
    const int rrow = wid * 32 + (lane >> 1);
    const int rseg = (lane & 1) * 32;
    _Float16* dst = Po + (((size_t)ks * BH_NUM + bh) * S_LEN + i0 + rrow) * 64 + rseg;
    #pragma unroll
    for (int i = 0; i < 4; ++i)
        *(half8*)&dst[8 * i] = *(const half8*)&Obuf[(size_t)rrow * 72 + rseg + 8 * i];
}

// ---------------------------------------------------------------------------
// merge partials + combine heads (exp2 domain for m):
// out[b][s][v] = sum_h (sum_p 2^{m_p-M} O_p) / (sum_p 2^{m_p-M} l_p)
// ---------------------------------------------------------------------------
__global__ __launch_bounds__(256) void merge_kernel(
    const _Float16* __restrict__ Po, const float2* __restrict__ Ml,
    float* __restrict__ out)
{
    const int b = blockIdx.y;
    const int s = blockIdx.x * 32 + (threadIdx.x >> 3);
    const int v0 = (threadIdx.x & 7) * 8;
    float acc[8] = {0, 0, 0, 0, 0, 0, 0, 0};
    #pragma unroll
    for (int h = 0; h < 8; ++h) {
        const int bh = b * 8 + h;
        float m[KSPLIT], l[KSPLIT];
        #pragma unroll
        for (int p = 0; p < KSPLIT; ++p) {
            const float2 v = Ml[((size_t)p * BH_NUM + bh) * S_LEN + s];
            m[p] = v.x; l[p] = v.y;
        }
        float M = fmaxf(m[0], m[1]);
        float L = 0.f, w[KSPLIT];
        #pragma unroll
        for (int p = 0; p < KSPLIT; ++p) { w[p] = exp2f(m[p] - M); L += w[p] * l[p]; }
        const float invL = 1.0f / L;
        #pragma unroll
        for (int p = 0; p < KSPLIT; ++p) {
            half8 o = *(const half8*)&Po[(((size_t)p * BH_NUM + bh) * S_LEN + s) * 64 + v0];
            const float wp = w[p] * invL;
            #pragma unroll
            for (int j = 0; j < 8; ++j) acc[j] += wp * (float)o[j];
        }
    }
    float4 o0 = {acc[0], acc[1], acc[2], acc[3]};
    float4 o1 = {acc[4], acc[5], acc[6], acc[7]};
    *(float4*)&out[((size_t)b * S_LEN + s) * 64 + v0] = o0;
    *(float4*)&out[((size_t)b * S_LEN + s) * 64 + v0 + 4] = o1;
}

// ---------------------------------------------------------------------------
extern "C" void kernel_launch(void* const* d_in, const int* in_sizes, int n_in,
                              void* d_out, int out_size, void* d_ws, size_t ws_size,
                              hipStream_t stream)
{
    const float* xs  = (const float*)d_in[0];
    const float* w_q = (const float*)d_in[1];
    const float* w_k = (const float*)d_in[2];
    const float* w_v = (const float*)d_in[3];
    const float* w_o = (const float*)d_in[4];
    const float* a_k = (const float*)d_in[5];
    float* out = (float*)d_out;

    char* w = (char*)d_ws;
    _Float16* Xh  = (_Float16*)w;  w += (size_t)B_NUM * S_LEN * E_DIM * 2;        // 4 MB
    _Float16* Wht = (_Float16*)w;  w += (size_t)3 * H_NUM * 64 * 512 * 2;         // 1.5 MB
    _Float16* akh = (_Float16*)w;  w += 33024;
    _Float16* Qh  = (_Float16*)w;  w += (size_t)BH_NUM * S_LEN * 64 * 2;
    _Float16* Kh  = (_Float16*)w;  w += (size_t)BH_NUM * S_LEN * 64 * 2;
    _Float16* Vt  = (_Float16*)w;  w += (size_t)BH_NUM * S_LEN * 64 * 2;
    _Float16* QAe = (_Float16*)w;  w += (size_t)BH_NUM * S_LEN * QAE_W * 2;       // 33.5 MB
    _Float16* Po  = (_Float16*)w;  w += (size_t)KSPLIT * BH_NUM * S_LEN * 64 * 2; // 8.4 MB
    float2*   Ml  = (float2*)w;                                                    // 0.5 MB

    cast_x_kernel<<<1024, 256, 0, stream>>>(xs, Xh);
    cast_wak_kernel<<<dim3(8, 8, 4), 256, 0, stream>>>(w_q, w_k, w_v, w_o, a_k, Wht, akh);
    proj_mfma_kernel<<<dim3(16, 16, 3), 256, 0, stream>>>(Xh, Wht, akh, Qh, Kh, Vt, QAe);
    attn_kernel<<<256, 512, 0, stream>>>(Qh, Kh, Vt, QAe, Po, Ml);
    merge_kernel<<<dim3(64, 2), 256, 0, stream>>>(Po, Ml, out);
}

// Round 14
// 80.060 us; speedup vs baseline: 1.7320x; 1.1233x over previous
//
#include <hip/hip_runtime.h>
#include <hip/hip_bf16.h>

#define S_LEN 2048
#define E_DIM 512
#define D_DIM 64
#define H_NUM 8
#define B_NUM 2
#define BH_NUM 16
#define NQA 257
#define QAE_W 512                 // clamp-extended QA row width
#define KSPLIT 2
#define NT (S_LEN / KSPLIT / 64)  // 16 tiles per block (interleaved stride 128)
#define QTILE 256                 // q-rows per attn block (8 waves x 32)

typedef _Float16 half8 __attribute__((ext_vector_type(8)));
typedef float f32x16 __attribute__((ext_vector_type(16)));
typedef unsigned int uint2v __attribute__((ext_vector_type(2)));
typedef unsigned int uint4v __attribute__((ext_vector_type(4)));

static __device__ __forceinline__ f32x16 MFMA(half8 a, half8 b, f32x16 c) {
    return __builtin_amdgcn_mfma_f32_32x32x16_f16(a, b, c, 0, 0, 0);
}
static __device__ __forceinline__ f32x16 ZERO16() {
    f32x16 z;
    #pragma unroll
    for (int i = 0; i < 16; ++i) z[i] = 0.f;
    return z;
}
static __device__ __forceinline__ unsigned int PKRTZ(float a, float b) {
    return __builtin_bit_cast(unsigned int, __builtin_amdgcn_cvt_pkrtz(a, b));
}

// ---------------------------------------------------------------------------
// cast xs (fp32) -> Xh (fp16)
// ---------------------------------------------------------------------------
__global__ __launch_bounds__(256) void cast_x_kernel(
    const float* __restrict__ xs, _Float16* __restrict__ Xh)
{
    const int idx = (blockIdx.x * 256 + threadIdx.x) * 8;
    float4 a = *(const float4*)&xs[idx];
    float4 b = *(const float4*)&xs[idx + 4];
    half8 o;
    o[0] = (_Float16)a.x; o[1] = (_Float16)a.y; o[2] = (_Float16)a.z; o[3] = (_Float16)a.w;
    o[4] = (_Float16)b.x; o[5] = (_Float16)b.y; o[6] = (_Float16)b.z; o[7] = (_Float16)b.w;
    *(half8*)&Xh[idx] = o;
}

// ---------------------------------------------------------------------------
// cast + transpose weights -> Wht[type][h][n=64][k=512] fp16  (z = 0,1,2)
// type 0 (w_q) scaled by 1/8 (softmax scale folded into Q).
// z == 3: cast a_k -> fp16 (first 9 (y*8+x) blocks)
// ---------------------------------------------------------------------------
__global__ __launch_bounds__(256) void cast_wak_kernel(
    const float* __restrict__ w_q, const float* __restrict__ w_k,
    const float* __restrict__ w_v, const float* __restrict__ w_o,
    const float* __restrict__ a_k,
    _Float16* __restrict__ Wht, _Float16* __restrict__ akh)
{
    __shared__ float T[64][68];
    const int type = blockIdx.z;
    const int t = threadIdx.x;
    if (type == 3) {
        const int bn = blockIdx.y * 8 + blockIdx.x;
        if (bn >= 9) return;
        const int idx = (bn * 256 + t) * 8;
        if (idx < NQA * 64) {
            float4 a = *(const float4*)&a_k[idx];
            float4 b = *(const float4*)&a_k[idx + 4];
            half8 o;
            o[0] = (_Float16)a.x; o[1] = (_Float16)a.y; o[2] = (_Float16)a.z; o[3] = (_Float16)a.w;
            o[4] = (_Float16)b.x; o[5] = (_Float16)b.y; o[6] = (_Float16)b.z; o[7] = (_Float16)b.w;
            *(half8*)&akh[idx] = o;
        }
        return;
    }
    const int kt = blockIdx.x, h = blockIdx.y;
    const float* W = (type == 0) ? w_q : (type == 1) ? w_k : w_v;
    const float scale = (type == 0) ? 0.125f : (type == 2 ? w_o[h] : 1.0f);
    const int kr = t >> 2, nseg = (t & 3) * 16;
    #pragma unroll
    for (int i = 0; i < 4; ++i)
        *(float4*)&T[kr][nseg + 4 * i] =
            *(const float4*)&W[((size_t)h * 512 + kt * 64 + kr) * 64 + nseg + 4 * i];
    __syncthreads();
    const int nr = t >> 2, kseg = (t & 3) * 16;
    _Float16* dst = Wht + ((size_t)(type * 8 + h) * 64 + nr) * 512 + kt * 64 + kseg;
    #pragma unroll
    for (int i = 0; i < 2; ++i) {
        half8 o;
        #pragma unroll
        for (int j = 0; j < 8; ++j) o[j] = (_Float16)(T[kseg + 8 * i + j][nr] * scale);
        *(half8*)&dst[8 * i] = o;
    }
}

// ---------------------------------------------------------------------------
// MFMA projections + fused QA (type 0).
// Phase A: out[128x64] = Xh[b](128 rows) * Wht[type][h]^T (K=512)
// Phase B (type==0 only): QAe[bh][row][idx+128] = Q[row].ak[idx] + padding,
// reusing the Q-tile already in LDS.
// grid (16 mtiles, 16 bh, 3 type), block 256 (4 waves x 32 rows)
// ---------------------------------------------------------------------------
__global__ __launch_bounds__(256) void proj_mfma_kernel(
    const _Float16* __restrict__ Xh, const _Float16* __restrict__ Wht,
    const _Float16* __restrict__ akh,
    _Float16* __restrict__ Qh, _Float16* __restrict__ Kh,
    _Float16* __restrict__ Vt, _Float16* __restrict__ QAe)
{
    __shared__ __align__(16) _Float16 raw[30208];   // 60416 B
    _Float16 (*Xlds)[128][72] = (_Float16(*)[128][72])raw;          // phase A
    _Float16 (*Wlds)[64][72]  = (_Float16(*)[64][72])(raw + 18432); // phase A
    _Float16* ob  = raw;                                            // [128][72] B
    _Float16 (*ak)[72] = (_Float16(*)[72])(raw + 9216);             // [288][72] B
    _Float16* SLo = raw + 29952;                                    // [128]
    _Float16* SHi = raw + 30080;                                    // [128]

    const int mt = blockIdx.x, bh = blockIdx.y, type = blockIdx.z;
    const int b = bh >> 3, h = bh & 7;
    const int m0 = mt * 128;
    const int t = threadIdx.x, wid = t >> 6, lane = t & 63;
    const int lq = lane & 31, lh = lane >> 5;

    const _Float16* W = Wht + (size_t)(type * 8 + h) * 64 * 512;
    const _Float16* X = Xh + ((size_t)b * S_LEN + m0) * 512;

    const int xrow = t >> 1, xseg = (t & 1) * 32;
    const int wrow = t >> 2, wseg = (t & 3) * 16;

    #pragma unroll
    for (int i = 0; i < 4; ++i)
        *(half8*)&Xlds[0][xrow][xseg + 8 * i] =
            *(const half8*)&X[(size_t)xrow * 512 + xseg + 8 * i];
    #pragma unroll
    for (int i = 0; i < 2; ++i)
        *(half8*)&Wlds[0][wrow][wseg + 8 * i] =
            *(const half8*)&W[(size_t)wrow * 512 + wseg + 8 * i];
    __syncthreads();

    f32x16 acc[2];
    acc[0] = ZERO16(); acc[1] = ZERO16();
    int cur = 0;
    for (int c = 0; c < 8; ++c) {
        half8 xst[4], wst[2];
        if (c < 7) {
            const int k0 = (c + 1) * 64;
            #pragma unroll
            for (int i = 0; i < 4; ++i)
                xst[i] = *(const half8*)&X[(size_t)xrow * 512 + k0 + xseg + 8 * i];
            #pragma unroll
            for (int i = 0; i < 2; ++i)
                wst[i] = *(const half8*)&W[(size_t)wrow * 512 + k0 + wseg + 8 * i];
        }
        #pragma unroll
        for (int kc = 0; kc < 4; ++kc) {
            half8 a  = *(const half8*)&Xlds[cur][wid * 32 + lq][kc * 16 + lh * 8];
            half8 b0 = *(const half8*)&Wlds[cur][lq][kc * 16 + lh * 8];
            half8 b1 = *(const half8*)&Wlds[cur][32 + lq][kc * 16 + lh * 8];
            acc[0] = MFMA(a, b0, acc[0]);
            acc[1] = MFMA(a, b1, acc[1]);
        }
        if (c < 7) {
            #pragma unroll
            for (int i = 0; i < 4; ++i)
                *(half8*)&Xlds[cur ^ 1][xrow][xseg + 8 * i] = xst[i];
            #pragma unroll
            for (int i = 0; i < 2; ++i)
                *(half8*)&Wlds[cur ^ 1][wrow][wseg + 8 * i] = wst[i];
        }
        __syncthreads();
        cur ^= 1;
    }

    // epilogue: acc -> ob
    #pragma unroll
    for (int n = 0; n < 2; ++n)
        #pragma unroll
        for (int r = 0; r < 16; ++r) {
            int row = wid * 32 + (r & 3) + ((r >> 2) << 3) + (lh << 2);
            ob[row * 72 + n * 32 + lq] = (_Float16)acc[n][r];
        }
    __syncthreads();

    if (type == 2) {
        const int v = t >> 2, sseg = (t & 3) * 32;
        _Float16* dst = Vt + ((size_t)bh * 64 + v) * S_LEN + m0 + sseg;
        #pragma unroll
        for (int i = 0; i < 4; ++i) {
            half8 o;
            #pragma unroll
            for (int j = 0; j < 8; ++j) o[j] = ob[(sseg + 8 * i + j) * 72 + v];
            *(half8*)&dst[8 * i] = o;
        }
        return;
    }

    {   // Qh / Kh store
        _Float16* P = (type == 0) ? Qh : Kh;
        const int row = t >> 1, seg = (t & 1) * 32;
        _Float16* dst = P + ((size_t)bh * S_LEN + m0 + row) * 64 + seg;
        #pragma unroll
        for (int i = 0; i < 4; ++i)
            *(half8*)&dst[8 * i] = *(const half8*)&ob[row * 72 + seg + 8 * i];
    }
    if (type != 0) return;

    // -------- phase B: fused QA (Q-tile already in ob) --------
    for (int r = t; r < 288; r += 256) {
        if (r < NQA) {
            #pragma unroll
            for (int i = 0; i < 8; ++i)
                *(half8*)&ak[r][8 * i] = *(const half8*)&akh[(size_t)r * 64 + 8 * i];
        } else {
            half8 z = {};
            #pragma unroll
            for (int i = 0; i < 8; ++i) *(half8*)&ak[r][8 * i] = z;
        }
    }
    __syncthreads();

    half8 qfr[4];
    #pragma unroll
    for (int kc = 0; kc < 4; ++kc)
        qfr[kc] = *(const half8*)&ob[(wid * 32 + lq) * 72 + kc * 16 + lh * 8];

    for (int nsub = 0; nsub < 9; ++nsub) {
        f32x16 qa = ZERO16();
        #pragma unroll
        for (int kc = 0; kc < 4; ++kc) {
            half8 bf = *(const half8*)&ak[nsub * 32 + lq][kc * 16 + lh * 8];
            qa = MFMA(qfr[kc], bf, qa);
        }
        const int col = nsub * 32 + lq;
        if (col < NQA) {
            #pragma unroll
            for (int r = 0; r < 16; ++r) {
                const int row = m0 + wid * 32 + (r & 3) + ((r >> 2) << 3) + (lh << 2);
                const _Float16 v = (_Float16)qa[r];
                QAe[((size_t)bh * S_LEN + row) * QAE_W + col + 128] = v;
                if (col == 0)   SLo[row - m0] = v;
                if (col == 256) SHi[row - m0] = v;
            }
        }
    }
    __syncthreads();

    const int prow = t >> 1, pseg = (t & 1) * 64;
    const _Float16 lo = SLo[prow], hi = SHi[prow];
    half8 vlo, vhi;
    #pragma unroll
    for (int j = 0; j < 8; ++j) { vlo[j] = lo; vhi[j] = hi; }
    _Float16* pb = QAe + ((size_t)bh * S_LEN + m0 + prow) * QAE_W;
    #pragma unroll
    for (int i = 0; i < 8; ++i) {
        *(half8*)&pb[pseg + 8 * i] = vlo;          // cols 0..127
        *(half8*)&pb[384 + pseg + 8 * i] = vhi;    // cols 384..511
    }
}

// ---------------------------------------------------------------------------
// Flash attention: 512-thread blocks (8 waves x 32 q-rows = 256 q-rows),
// KSPLIT=2 with INTERLEAVED key tiles: block ks processes keys
// (jt*2+ks)*64 for jt=0..15 -> every block spans the full key range and
// gets the SAME ~3 in-band tiles (load-balanced across all CUs; previously
// diagonal blocks carried 2x the work while off-diagonal CUs idled).
// Double-buffered K/V + per-wave bias band prefetched 1 tile ahead.
// ---------------------------------------------------------------------------
__global__ __launch_bounds__(512) void attn_kernel(
    const _Float16* __restrict__ Qh, const _Float16* __restrict__ Kh,
    const _Float16* __restrict__ Vt, const _Float16* __restrict__ QAe,
    _Float16* __restrict__ Po, float2* __restrict__ Ml)
{
    __shared__ __align__(16) char smraw[36864];
    _Float16 (*Klds)[64][72] = (_Float16(*)[64][72])smraw;             // [2][64][72]
    _Float16 (*Vlds)[64][72] = (_Float16(*)[64][72])(smraw + 18432);   // [2][64][72]
    _Float16* Obuf = (_Float16*)smraw;                                 // [256][72]
    __shared__ __align__(16) _Float16 Bnd[8][32][128];                 // 64KB band

    const int p0 = blockIdx.x;                 // 0..255
    const int nb = (p0 & 7) * 32 + (p0 >> 3);  // XCD swizzle: 2 bh per XCD
    const int bh = nb >> 4;
    const int rem = nb & 15;
    const int qt = rem & 7, ks = rem >> 3;
    const int i0 = qt * QTILE;

    const int t = threadIdx.x, wid = t >> 6, lane = t & 63;
    const int lq = lane & 31, lh = lane >> 5;
    const int i0w = i0 + wid * 32;             // this wave's 32 q-rows
    const int qg = i0w + lq;

    half8 qf[4];
    #pragma unroll
    for (int kc = 0; kc < 4; ++kc)
        qf[kc] = *(const half8*)&Qh[((size_t)bh * S_LEN + qg) * 64 + kc * 16 + lh * 8];

    const _Float16* qaeRow = QAe + ((size_t)bh * S_LEN + qg) * QAE_W;
    const float qa_lo = (float)qaeRow[128];   // idx 0
    const float qa_hi = (float)qaeRow[384];   // idx 256
    const _Float16* BndSrc = QAe + ((size_t)bh * S_LEN + i0w) * QAE_W;

    float rm = -1e30f, rl = 0.f;
    f32x16 acco[2];
    acco[0] = ZERO16(); acco[1] = ZERO16();

    // staging: 512 threads, each 16B of K-tile and 16B of Vt-tile per KV tile
    const int srow = t >> 3, sseg = (t & 7) * 8;
    const _Float16* Kbase = Kh + (size_t)bh * S_LEN * 64;
    const _Float16* Vbase = Vt + ((size_t)bh * 64 + srow) * S_LEN;

    const int brow = lane >> 4;                // 0..3 (band stage row group)
    const int bcol = (lane & 15) * 8;          // band stage col (halves)

    half8 kst, vst, breg[8];
    // tile jt keys: (jt*2+ks)*64 = ks*64 + jt*128
    const int kv0 = ks * 64;
    *(half8*)&Klds[0][srow][sseg] = *(const half8*)&Kbase[(size_t)(kv0 + srow) * 64 + sseg];
    *(half8*)&Vlds[0][srow][sseg] = *(const half8*)&Vbase[kv0 + sseg];
    kst = *(const half8*)&Kbase[(size_t)(kv0 + 128 + srow) * 64 + sseg];
    vst = *(const half8*)&Vbase[kv0 + 128 + sseg];

    // band prefetch for tile 0
    bool inb_next;
    {
        const int d0 = kv0 - i0w;
        inb_next = (d0 < 159) && (d0 > -191);
        if (inb_next) {
            const int cw0n = (d0 + 225) & ~7;
            #pragma unroll
            for (int ps = 0; ps < 8; ++ps)
                breg[ps] = *(const half8*)&BndSrc[(size_t)(ps * 4 + brow) * QAE_W + cw0n + bcol];
        }
    }
    __syncthreads();

    for (int jt = 0; jt < NT; ++jt) {
        const int cur = jt & 1;
        if (jt) __syncthreads();
        if (jt + 1 < NT) {
            *(half8*)&Klds[cur ^ 1][srow][sseg] = kst;
            *(half8*)&Vlds[cur ^ 1][srow][sseg] = vst;
        }
        if (jt + 2 < NT) {
            const int jg = kv0 + (jt + 2) * 128;
            kst = *(const half8*)&Kbase[(size_t)(jg + srow) * 64 + sseg];
            vst = *(const half8*)&Vbase[jg + sseg];
        }

        const int diff = kv0 + jt * 128 - i0w;
        const bool inband = inb_next;
        const int cw0 = (diff + 225) & ~7;     // 16B-aligned band start (c')

        // write this tile's (prefetched) band regs -> per-wave LDS
        if (inband) {
            #pragma unroll
            for (int ps = 0; ps < 8; ++ps)
                *(half8*)&Bnd[wid][ps * 4 + brow][bcol] = breg[ps];
        }
        // prefetch next tile's band (next tile is +128 keys away)
        {
            const int dn = diff + 128;
            inb_next = (jt + 1 < NT) && (dn < 159) && (dn > -191);
            if (inb_next) {
                const int cw0n = (dn + 225) & ~7;
                #pragma unroll
                for (int ps = 0; ps < 8; ++ps)
                    breg[ps] = *(const half8*)&BndSrc[(size_t)(ps * 4 + brow) * QAE_W + cw0n + bcol];
            }
        }

        // S^T = K . Q^T
        f32x16 accs[2];
        accs[0] = ZERO16(); accs[1] = ZERO16();
        __builtin_amdgcn_s_setprio(1);
        #pragma unroll
        for (int kc = 0; kc < 4; ++kc) {
            half8 ka = *(const half8*)&Klds[cur][lq][kc * 16 + lh * 8];
            half8 kb = *(const half8*)&Klds[cur][32 + lq][kc * 16 + lh * 8];
            accs[0] = MFMA(ka, qf[kc], accs[0]);
            accs[1] = MFMA(kb, qf[kc], accs[1]);
        }
        __builtin_amdgcn_s_setprio(0);

        const bool allhi = (diff >= 159);
        const bool alllo = (diff <= -191);
        float bunif = 0.f;
        if (allhi) bunif = qa_hi;
        else if (alllo) bunif = qa_lo;
        else {
            asm volatile("s_waitcnt lgkmcnt(0)" ::: "memory");
            __builtin_amdgcn_sched_barrier(0);
            const int pb = diff + 256 - cw0 - lq;   // + keyoff in [0,127]
            #pragma unroll
            for (int m = 0; m < 2; ++m)
                #pragma unroll
                for (int r = 0; r < 16; ++r) {
                    const int keyoff = m * 32 + (r & 3) + ((r >> 2) << 3) + (lh << 2);
                    accs[m][r] += (float)Bnd[wid][lq][pb + keyoff];
                }
        }

        // online softmax: tree max, shift-folded uniform bias
        float t8[8];
        #pragma unroll
        for (int i = 0; i < 8; ++i)
            t8[i] = fmaxf(fmaxf(accs[0][i], accs[0][i + 8]),
                          fmaxf(accs[1][i], accs[1][i + 8]));
        float tmax = fmaxf(fmaxf(fmaxf(t8[0], t8[1]), fmaxf(t8[2], t8[3])),
                           fmaxf(fmaxf(t8[4], t8[5]), fmaxf(t8[6], t8[7])));
        tmax = fmaxf(tmax, __shfl_xor(tmax, 32));
        const float mnew = fmaxf(rm, tmax + bunif);
        const bool resc = __any(mnew > rm);
        const float corr = __expf(rm - mnew);
        const float shift = mnew - bunif;
        rm = mnew;

        #pragma unroll
        for (int m = 0; m < 2; ++m)
            #pragma unroll
            for (int r = 0; r < 16; ++r)
                accs[m][r] = __expf(accs[m][r] - shift);

        float s8[8];
        #pragma unroll
        for (int i = 0; i < 8; ++i)
            s8[i] = (accs[0][i] + accs[0][i + 8]) + (accs[1][i] + accs[1][i + 8]);
        float psum = ((s8[0] + s8[1]) + (s8[2] + s8[3])) +
                     ((s8[4] + s8[5]) + (s8[6] + s8[7]));
        psum += __shfl_xor(psum, 32);

        if (resc) {
            rl = rl * corr + psum;
            #pragma unroll
            for (int n = 0; n < 2; ++n)
                #pragma unroll
                for (int r = 0; r < 16; ++r) acco[n][r] *= corr;
        } else {
            rl += psum;
        }

        // pack P -> PV B-fragments in-register (cvt_pkrtz + permlane32_swap)
        half8 pf[4];
        #pragma unroll
        for (int kc = 0; kc < 4; ++kc) {
            const int m = kc >> 1, rb = (kc & 1) * 8;
            unsigned int a01 = PKRTZ(accs[m][rb + 0], accs[m][rb + 1]);
            unsigned int a45 = PKRTZ(accs[m][rb + 4], accs[m][rb + 5]);
            unsigned int a23 = PKRTZ(accs[m][rb + 2], accs[m][rb + 3]);
            unsigned int a67 = PKRTZ(accs[m][rb + 6], accs[m][rb + 7]);
            uint2v r02 = __builtin_amdgcn_permlane32_swap(a01, a45, false, false);
            uint2v r13 = __builtin_amdgcn_permlane32_swap(a23, a67, false, false);
            uint4v wv;
            wv[0] = r02[0]; wv[1] = r13[0]; wv[2] = r02[1]; wv[3] = r13[1];
            pf[kc] = __builtin_bit_cast(half8, wv);
        }

        // O^T += V^T . P^T
        __builtin_amdgcn_s_setprio(1);
        #pragma unroll
        for (int kc = 0; kc < 4; ++kc) {
            half8 v0 = *(const half8*)&Vlds[cur][lq][kc * 16 + lh * 8];
            half8 v1 = *(const half8*)&Vlds[cur][32 + lq][kc * 16 + lh * 8];
            acco[0] = MFMA(v0, pf[kc], acco[0]);
            acco[1] = MFMA(v1, pf[kc], acco[1]);
        }
        __builtin_amdgcn_s_setprio(0);
    }

    // epilogue: all waves done with K/V LDS -> overlay O-buffer
    __syncthreads();
    const int orow = wid * 32 + lq;
    #pragma unroll
    for (int n = 0; n < 2; ++n)
        #pragma unroll
        for (int rq = 0; rq < 4; ++rq) {
            uint2v hv;
            hv[0] = PKRTZ(acco[n][rq * 4 + 0], acco[n][rq * 4 + 1]);
            hv[1] = PKRTZ(acco[n][rq * 4 + 2], acco[n][rq * 4 + 3]);
            *(uint2v*)&Obuf[(size_t)orow * 72 + n * 32 + rq * 8 + lh * 4] = hv;
        }
    if (lh == 0)
        Ml[((size_t)ks * BH_NUM + bh) * S_LEN + qg] = make_float2(rm, rl);
    asm volatile("s_waitcnt lgkmcnt(0)" ::: "memory");
    __builtin_amdgcn_sched_barrier(0);
    const int rrow = wid * 32 + (lane >> 1);
    const int rseg = (lane & 1) * 32;
    _Float16* dst = Po + (((size_t)ks * BH_NUM + bh) * S_LEN + i0 + rrow) * 64 + rseg;
    #pragma unroll
    for (int i = 0; i < 4; ++i)
        *(half8*)&dst[8 * i] = *(const half8*)&Obuf[(size_t)rrow * 72 + rseg + 8 * i];
}

// ---------------------------------------------------------------------------
// merge partials + combine heads:
// out[b][s][v] = sum_h (sum_p e^{m_p-M} O_p) / (sum_p e^{m_p-M} l_p)
// ---------------------------------------------------------------------------
__global__ __launch_bounds__(256) void merge_kernel(
    const _Float16* __restrict__ Po, const float2* __restrict__ Ml,
    float* __restrict__ out)
{
    const int b = blockIdx.y;
    const int s = blockIdx.x * 32 + (threadIdx.x >> 3);
    const int v0 = (threadIdx.x & 7) * 8;
    float acc[8] = {0, 0, 0, 0, 0, 0, 0, 0};
    #pragma unroll
    for (int h = 0; h < 8; ++h) {
        const int bh = b * 8 + h;
        float m[KSPLIT], l[KSPLIT];
        #pragma unroll
        for (int p = 0; p < KSPLIT; ++p) {
            const float2 v = Ml[((size_t)p * BH_NUM + bh) * S_LEN + s];
            m[p] = v.x; l[p] = v.y;
        }
        float M = fmaxf(m[0], m[1]);
        float L = 0.f, w[KSPLIT];
        #pragma unroll
        for (int p = 0; p < KSPLIT; ++p) { w[p] = __expf(m[p] - M); L += w[p] * l[p]; }
        const float invL = 1.0f / L;
        #pragma unroll
        for (int p = 0; p < KSPLIT; ++p) {
            half8 o = *(const half8*)&Po[(((size_t)p * BH_NUM + bh) * S_LEN + s) * 64 + v0];
            const float wp = w[p] * invL;
            #pragma unroll
            for (int j = 0; j < 8; ++j) acc[j] += wp * (float)o[j];
        }
    }
    float4 o0 = {acc[0], acc[1], acc[2], acc[3]};
    float4 o1 = {acc[4], acc[5], acc[6], acc[7]};
    *(float4*)&out[((size_t)b * S_LEN + s) * 64 + v0] = o0;
    *(float4*)&out[((size_t)b * S_LEN + s) * 64 + v0 + 4] = o1;
}

// ---------------------------------------------------------------------------
extern "C" void kernel_launch(void* const* d_in, const int* in_sizes, int n_in,
                              void* d_out, int out_size, void* d_ws, size_t ws_size,
                              hipStream_t stream)
{
    const float* xs  = (const float*)d_in[0];
    const float* w_q = (const float*)d_in[1];
    const float* w_k = (const float*)d_in[2];
    const float* w_v = (const float*)d_in[3];
    const float* w_o = (const float*)d_in[4];
    const float* a_k = (const float*)d_in[5];
    float* out = (float*)d_out;

    char* w = (char*)d_ws;
    _Float16* Xh  = (_Float16*)w;  w += (size_t)B_NUM * S_LEN * E_DIM * 2;        // 4 MB
    _Float16* Wht = (_Float16*)w;  w += (size_t)3 * H_NUM * 64 * 512 * 2;         // 1.5 MB
    _Float16* akh = (_Float16*)w;  w += 33024;
    _Float16* Qh  = (_Float16*)w;  w += (size_t)BH_NUM * S_LEN * 64 * 2;
    _Float16* Kh  = (_Float16*)w;  w += (size_t)BH_NUM * S_LEN * 64 * 2;
    _Float16* Vt  = (_Float16*)w;  w += (size_t)BH_NUM * S_LEN * 64 * 2;
    _Float16* QAe = (_Float16*)w;  w += (size_t)BH_NUM * S_LEN * QAE_W * 2;       // 33.5 MB
    _Float16* Po  = (_Float16*)w;  w += (size_t)KSPLIT * BH_NUM * S_LEN * 64 * 2; // 8.4 MB
    float2*   Ml  = (float2*)w;                                                    // 0.5 MB

    cast_x_kernel<<<1024, 256, 0, stream>>>(xs, Xh);
    cast_wak_kernel<<<dim3(8, 8, 4), 256, 0, stream>>>(w_q, w_k, w_v, w_o, a_k, Wht, akh);
    proj_mfma_kernel<<<dim3(16, 16, 3), 256, 0, stream>>>(Xh, Wht, akh, Qh, Kh, Vt, QAe);
    attn_kernel<<<256, 512, 0, stream>>>(Qh, Kh, Vt, QAe, Po, Ml);
    merge_kernel<<<dim3(64, 2), 256, 0, stream>>>(Po, Ml, out);
}

// Round 15
// 79.756 us; speedup vs baseline: 1.7386x; 1.0038x over previous
//
#include <hip/hip_runtime.h>
#include <hip/hip_bf16.h>

#define S_LEN 2048
#define E_DIM 512
#define D_DIM 64
#define H_NUM 8
#define B_NUM 2
#define BH_NUM 16
#define NQA 257
#define QAE_W 512                 // clamp-extended QA row width
#define KSPLIT 2
#define NP 8                      // 8 pairs of 128 keys (stride 256, offset ks*128)
#define QTILE 256                 // q-rows per attn block (8 waves x 32)
#define BNDW 176                  // band width (covers 166-wide pair span)

typedef _Float16 half8 __attribute__((ext_vector_type(8)));
typedef float f32x16 __attribute__((ext_vector_type(16)));
typedef unsigned int uint2v __attribute__((ext_vector_type(2)));
typedef unsigned int uint4v __attribute__((ext_vector_type(4)));

static __device__ __forceinline__ f32x16 MFMA(half8 a, half8 b, f32x16 c) {
    return __builtin_amdgcn_mfma_f32_32x32x16_f16(a, b, c, 0, 0, 0);
}
static __device__ __forceinline__ f32x16 ZERO16() {
    f32x16 z;
    #pragma unroll
    for (int i = 0; i < 16; ++i) z[i] = 0.f;
    return z;
}
static __device__ __forceinline__ unsigned int PKRTZ(float a, float b) {
    return __builtin_bit_cast(unsigned int, __builtin_amdgcn_cvt_pkrtz(a, b));
}

// ---------------------------------------------------------------------------
// cast xs (fp32) -> Xh (fp16)
// ---------------------------------------------------------------------------
__global__ __launch_bounds__(256) void cast_x_kernel(
    const float* __restrict__ xs, _Float16* __restrict__ Xh)
{
    const int idx = (blockIdx.x * 256 + threadIdx.x) * 8;
    float4 a = *(const float4*)&xs[idx];
    float4 b = *(const float4*)&xs[idx + 4];
    half8 o;
    o[0] = (_Float16)a.x; o[1] = (_Float16)a.y; o[2] = (_Float16)a.z; o[3] = (_Float16)a.w;
    o[4] = (_Float16)b.x; o[5] = (_Float16)b.y; o[6] = (_Float16)b.z; o[7] = (_Float16)b.w;
    *(half8*)&Xh[idx] = o;
}

// ---------------------------------------------------------------------------
// cast + transpose weights -> Wht[type][h][n=64][k=512] fp16  (z = 0,1,2)
// type 0 (w_q) scaled by 1/8. z == 3: cast a_k -> fp16.
// ---------------------------------------------------------------------------
__global__ __launch_bounds__(256) void cast_wak_kernel(
    const float* __restrict__ w_q, const float* __restrict__ w_k,
    const float* __restrict__ w_v, const float* __restrict__ w_o,
    const float* __restrict__ a_k,
    _Float16* __restrict__ Wht, _Float16* __restrict__ akh)
{
    __shared__ float T[64][68];
    const int type = blockIdx.z;
    const int t = threadIdx.x;
    if (type == 3) {
        const int bn = blockIdx.y * 8 + blockIdx.x;
        if (bn >= 9) return;
        const int idx = (bn * 256 + t) * 8;
        if (idx < NQA * 64) {
            float4 a = *(const float4*)&a_k[idx];
            float4 b = *(const float4*)&a_k[idx + 4];
            half8 o;
            o[0] = (_Float16)a.x; o[1] = (_Float16)a.y; o[2] = (_Float16)a.z; o[3] = (_Float16)a.w;
            o[4] = (_Float16)b.x; o[5] = (_Float16)b.y; o[6] = (_Float16)b.z; o[7] = (_Float16)b.w;
            *(half8*)&akh[idx] = o;
        }
        return;
    }
    const int kt = blockIdx.x, h = blockIdx.y;
    const float* W = (type == 0) ? w_q : (type == 1) ? w_k : w_v;
    const float scale = (type == 0) ? 0.125f : (type == 2 ? w_o[h] : 1.0f);
    const int kr = t >> 2, nseg = (t & 3) * 16;
    #pragma unroll
    for (int i = 0; i < 4; ++i)
        *(float4*)&T[kr][nseg + 4 * i] =
            *(const float4*)&W[((size_t)h * 512 + kt * 64 + kr) * 64 + nseg + 4 * i];
    __syncthreads();
    const int nr = t >> 2, kseg = (t & 3) * 16;
    _Float16* dst = Wht + ((size_t)(type * 8 + h) * 64 + nr) * 512 + kt * 64 + kseg;
    #pragma unroll
    for (int i = 0; i < 2; ++i) {
        half8 o;
        #pragma unroll
        for (int j = 0; j < 8; ++j) o[j] = (_Float16)(T[kseg + 8 * i + j][nr] * scale);
        *(half8*)&dst[8 * i] = o;
    }
}

// ---------------------------------------------------------------------------
// MFMA projections + fused QA (type 0). Same as r14 (proven).
// ---------------------------------------------------------------------------
__global__ __launch_bounds__(256) void proj_mfma_kernel(
    const _Float16* __restrict__ Xh, const _Float16* __restrict__ Wht,
    const _Float16* __restrict__ akh,
    _Float16* __restrict__ Qh, _Float16* __restrict__ Kh,
    _Float16* __restrict__ Vt, _Float16* __restrict__ QAe)
{
    __shared__ __align__(16) _Float16 raw[30208];   // 60416 B
    _Float16 (*Xlds)[128][72] = (_Float16(*)[128][72])raw;          // phase A
    _Float16 (*Wlds)[64][72]  = (_Float16(*)[64][72])(raw + 18432); // phase A
    _Float16* ob  = raw;                                            // [128][72] B
    _Float16 (*ak)[72] = (_Float16(*)[72])(raw + 9216);             // [288][72] B
    _Float16* SLo = raw + 29952;                                    // [128]
    _Float16* SHi = raw + 30080;                                    // [128]

    const int mt = blockIdx.x, bh = blockIdx.y, type = blockIdx.z;
    const int b = bh >> 3, h = bh & 7;
    const int m0 = mt * 128;
    const int t = threadIdx.x, wid = t >> 6, lane = t & 63;
    const int lq = lane & 31, lh = lane >> 5;

    const _Float16* W = Wht + (size_t)(type * 8 + h) * 64 * 512;
    const _Float16* X = Xh + ((size_t)b * S_LEN + m0) * 512;

    const int xrow = t >> 1, xseg = (t & 1) * 32;
    const int wrow = t >> 2, wseg = (t & 3) * 16;

    #pragma unroll
    for (int i = 0; i < 4; ++i)
        *(half8*)&Xlds[0][xrow][xseg + 8 * i] =
            *(const half8*)&X[(size_t)xrow * 512 + xseg + 8 * i];
    #pragma unroll
    for (int i = 0; i < 2; ++i)
        *(half8*)&Wlds[0][wrow][wseg + 8 * i] =
            *(const half8*)&W[(size_t)wrow * 512 + wseg + 8 * i];
    __syncthreads();

    f32x16 acc[2];
    acc[0] = ZERO16(); acc[1] = ZERO16();
    int cur = 0;
    for (int c = 0; c < 8; ++c) {
        half8 xst[4], wst[2];
        if (c < 7) {
            const int k0 = (c + 1) * 64;
            #pragma unroll
            for (int i = 0; i < 4; ++i)
                xst[i] = *(const half8*)&X[(size_t)xrow * 512 + k0 + xseg + 8 * i];
            #pragma unroll
            for (int i = 0; i < 2; ++i)
                wst[i] = *(const half8*)&W[(size_t)wrow * 512 + k0 + wseg + 8 * i];
        }
        #pragma unroll
        for (int kc = 0; kc < 4; ++kc) {
            half8 a  = *(const half8*)&Xlds[cur][wid * 32 + lq][kc * 16 + lh * 8];
            half8 b0 = *(const half8*)&Wlds[cur][lq][kc * 16 + lh * 8];
            half8 b1 = *(const half8*)&Wlds[cur][32 + lq][kc * 16 + lh * 8];
            acc[0] = MFMA(a, b0, acc[0]);
            acc[1] = MFMA(a, b1, acc[1]);
        }
        if (c < 7) {
            #pragma unroll
            for (int i = 0; i < 4; ++i)
                *(half8*)&Xlds[cur ^ 1][xrow][xseg + 8 * i] = xst[i];
            #pragma unroll
            for (int i = 0; i < 2; ++i)
                *(half8*)&Wlds[cur ^ 1][wrow][wseg + 8 * i] = wst[i];
        }
        __syncthreads();
        cur ^= 1;
    }

    // epilogue: acc -> ob
    #pragma unroll
    for (int n = 0; n < 2; ++n)
        #pragma unroll
        for (int r = 0; r < 16; ++r) {
            int row = wid * 32 + (r & 3) + ((r >> 2) << 3) + (lh << 2);
            ob[row * 72 + n * 32 + lq] = (_Float16)acc[n][r];
        }
    __syncthreads();

    if (type == 2) {
        const int v = t >> 2, sseg = (t & 3) * 32;
        _Float16* dst = Vt + ((size_t)bh * 64 + v) * S_LEN + m0 + sseg;
        #pragma unroll
        for (int i = 0; i < 4; ++i) {
            half8 o;
            #pragma unroll
            for (int j = 0; j < 8; ++j) o[j] = ob[(sseg + 8 * i + j) * 72 + v];
            *(half8*)&dst[8 * i] = o;
        }
        return;
    }

    {   // Qh / Kh store
        _Float16* P = (type == 0) ? Qh : Kh;
        const int row = t >> 1, seg = (t & 1) * 32;
        _Float16* dst = P + ((size_t)bh * S_LEN + m0 + row) * 64 + seg;
        #pragma unroll
        for (int i = 0; i < 4; ++i)
            *(half8*)&dst[8 * i] = *(const half8*)&ob[row * 72 + seg + 8 * i];
    }
    if (type != 0) return;

    // -------- phase B: fused QA --------
    for (int r = t; r < 288; r += 256) {
        if (r < NQA) {
            #pragma unroll
            for (int i = 0; i < 8; ++i)
                *(half8*)&ak[r][8 * i] = *(const half8*)&akh[(size_t)r * 64 + 8 * i];
        } else {
            half8 z = {};
            #pragma unroll
            for (int i = 0; i < 8; ++i) *(half8*)&ak[r][8 * i] = z;
        }
    }
    __syncthreads();

    half8 qfr[4];
    #pragma unroll
    for (int kc = 0; kc < 4; ++kc)
        qfr[kc] = *(const half8*)&ob[(wid * 32 + lq) * 72 + kc * 16 + lh * 8];

    for (int nsub = 0; nsub < 9; ++nsub) {
        f32x16 qa = ZERO16();
        #pragma unroll
        for (int kc = 0; kc < 4; ++kc) {
            half8 bf = *(const half8*)&ak[nsub * 32 + lq][kc * 16 + lh * 8];
            qa = MFMA(qfr[kc], bf, qa);
        }
        const int col = nsub * 32 + lq;
        if (col < NQA) {
            #pragma unroll
            for (int r = 0; r < 16; ++r) {
                const int row = m0 + wid * 32 + (r & 3) + ((r >> 2) << 3) + (lh << 2);
                const _Float16 v = (_Float16)qa[r];
                QAe[((size_t)bh * S_LEN + row) * QAE_W + col + 128] = v;
                if (col == 0)   SLo[row - m0] = v;
                if (col == 256) SHi[row - m0] = v;
            }
        }
    }
    __syncthreads();

    const int prow = t >> 1, pseg = (t & 1) * 64;
    const _Float16 lo = SLo[prow], hi = SHi[prow];
    half8 vlo, vhi;
    #pragma unroll
    for (int j = 0; j < 8; ++j) { vlo[j] = lo; vhi[j] = hi; }
    _Float16* pb = QAe + ((size_t)bh * S_LEN + m0 + prow) * QAE_W;
    #pragma unroll
    for (int i = 0; i < 8; ++i) {
        *(half8*)&pb[pseg + 8 * i] = vlo;          // cols 0..127
        *(half8*)&pb[384 + pseg + 8 * i] = vhi;    // cols 384..511
    }
}

// ---------------------------------------------------------------------------
// Flash attention: 512-thread blocks (8 waves x 32 q-rows), KSPLIT=2,
// grid 256 (1/CU, XCD-swizzled). 128-KEY PAIRS: one softmax per pair
// (halves per-tile fixed costs; QK/PV are 16-MFMA bursts). Pairs are
// contiguous 128 keys at stride 256 (offset ks*128) -> in-band pairs
// balanced across blocks. Per-sub-tile uniform/banded bias handling:
// full-uniform pairs shift-fold; mixed pairs add endpoint constants
// explicitly for the uniform half and band-read the other.
// ---------------------------------------------------------------------------
__global__ __launch_bounds__(512) void attn_kernel(
    const _Float16* __restrict__ Qh, const _Float16* __restrict__ Kh,
    const _Float16* __restrict__ Vt, const _Float16* __restrict__ QAe,
    _Float16* __restrict__ Po, float2* __restrict__ Ml)
{
    __shared__ __align__(16) char smraw[36864];
    _Float16 (*Klds)[64][72] = (_Float16(*)[64][72])smraw;             // [2][64][72] A/B
    _Float16 (*Vlds)[64][72] = (_Float16(*)[64][72])(smraw + 18432);   // [2][64][72] A/B
    _Float16* Obuf = (_Float16*)smraw;                                 // [256][72]
    __shared__ __align__(16) _Float16 Bnd[8][32][BNDW];                // 90112 B

    const int p0 = blockIdx.x;                 // 0..255
    const int nb = (p0 & 7) * 32 + (p0 >> 3);  // XCD swizzle
    const int bh = nb >> 4;
    const int rem = nb & 15;
    const int qt = rem & 7, ks = rem >> 3;
    const int i0 = qt * QTILE;
    const int kv0 = ks * 128;                  // pair p keys: p*256 + kv0 + [0,128)

    const int t = threadIdx.x, wid = t >> 6, lane = t & 63;
    const int lq = lane & 31, lh = lane >> 5;
    const int i0w = i0 + wid * 32;
    const int qg = i0w + lq;

    half8 qf[4];
    #pragma unroll
    for (int kc = 0; kc < 4; ++kc)
        qf[kc] = *(const half8*)&Qh[((size_t)bh * S_LEN + qg) * 64 + kc * 16 + lh * 8];

    const _Float16* qaeRow = QAe + ((size_t)bh * S_LEN + qg) * QAE_W;
    const float qa_lo = (float)qaeRow[128];   // idx 0
    const float qa_hi = (float)qaeRow[384];   // idx 256
    const _Float16* BndSrc = QAe + ((size_t)bh * S_LEN + i0w) * QAE_W;

    float rm = -1e30f, rl = 0.f;
    f32x16 acco[2];
    acco[0] = ZERO16(); acco[1] = ZERO16();

    // K/V staging: 512 threads, 16B per sub-tile each (K and V)
    const int srow = t >> 3, sseg = (t & 7) * 8;
    const _Float16* Kbase = Kh + (size_t)bh * S_LEN * 64;
    const _Float16* Vbase = Vt + ((size_t)bh * 64 + srow) * S_LEN;

    // band staging: 2 lanes per row, 11 x 16B per lane (176 halves/row)
    const int brow = lane >> 1;
    const int bhalf = (lane & 1) * 88;

    half8 kA, kB, vA, vB, breg[11];
    // prologue: pair 0 -> LDS
    {
        const int js = kv0;
        *(half8*)&Klds[0][srow][sseg] = *(const half8*)&Kbase[(size_t)(js + srow) * 64 + sseg];
        *(half8*)&Klds[1][srow][sseg] = *(const half8*)&Kbase[(size_t)(js + 64 + srow) * 64 + sseg];
        *(half8*)&Vlds[0][srow][sseg] = *(const half8*)&Vbase[js + sseg];
        *(half8*)&Vlds[1][srow][sseg] = *(const half8*)&Vbase[js + 64 + sseg];
        // pair 1 -> regs
        const int j1 = 256 + kv0;
        kA = *(const half8*)&Kbase[(size_t)(j1 + srow) * 64 + sseg];
        kB = *(const half8*)&Kbase[(size_t)(j1 + 64 + srow) * 64 + sseg];
        vA = *(const half8*)&Vbase[j1 + sseg];
        vB = *(const half8*)&Vbase[j1 + 64 + sseg];
    }
    // band prefetch for pair 0
    bool bA_n, bB_n; int cw0_n = 0;
    {
        const int d = kv0 - i0w;
        bA_n = (d > -191) && (d < 159);
        bB_n = (d > -255) && (d < 95);
        if (bA_n || bB_n) {
            const int dFB = bA_n ? d : d + 64;
            cw0_n = (dFB + 225) & ~7;
            cw0_n = cw0_n > 336 ? 336 : cw0_n;
            #pragma unroll
            for (int i = 0; i < 11; ++i)
                breg[i] = *(const half8*)&BndSrc[(size_t)brow * QAE_W + cw0_n + bhalf + i * 8];
        }
    }
    __syncthreads();

    for (int p = 0; p < NP; ++p) {
        const int diff = p * 256 + kv0 - i0w;
        const bool bA = bA_n, bB = bB_n;
        const int cw0 = cw0_n;

        // write this pair's (prefetched) band regs -> per-wave LDS
        if (bA || bB) {
            #pragma unroll
            for (int i = 0; i < 11; ++i)
                *(half8*)&Bnd[wid][brow][bhalf + i * 8] = breg[i];
        }

        // S^T = K . Q^T  (both sub-tiles, 16 MFMA)
        f32x16 accs[4];
        accs[0] = ZERO16(); accs[1] = ZERO16(); accs[2] = ZERO16(); accs[3] = ZERO16();
        __builtin_amdgcn_s_setprio(1);
        #pragma unroll
        for (int kc = 0; kc < 4; ++kc) {
            half8 a0 = *(const half8*)&Klds[0][lq][kc * 16 + lh * 8];
            half8 a1 = *(const half8*)&Klds[0][32 + lq][kc * 16 + lh * 8];
            half8 b0 = *(const half8*)&Klds[1][lq][kc * 16 + lh * 8];
            half8 b1 = *(const half8*)&Klds[1][32 + lq][kc * 16 + lh * 8];
            accs[0] = MFMA(a0, qf[kc], accs[0]);
            accs[1] = MFMA(a1, qf[kc], accs[1]);
            accs[2] = MFMA(b0, qf[kc], accs[2]);
            accs[3] = MFMA(b1, qf[kc], accs[3]);
        }
        __builtin_amdgcn_s_setprio(0);

        // bias
        float bunif = 0.f;
        if (diff >= 159) {
            bunif = qa_hi;
        } else if (diff <= -255) {
            bunif = qa_lo;
        } else {
            asm volatile("s_waitcnt lgkmcnt(0)" ::: "memory");
            __builtin_amdgcn_sched_barrier(0);
            const int pbA = diff + 256 - cw0 - lq;
            const int pbB = pbA + 64;
            if (bA) {
                #pragma unroll
                for (int m = 0; m < 2; ++m)
                    #pragma unroll
                    for (int r = 0; r < 16; ++r) {
                        const int keyoff = m * 32 + (r & 3) + ((r >> 2) << 3) + (lh << 2);
                        accs[m][r] += (float)Bnd[wid][lq][pbA + keyoff];
                    }
            } else {
                #pragma unroll
                for (int m = 0; m < 2; ++m)
                    #pragma unroll
                    for (int r = 0; r < 16; ++r) accs[m][r] += qa_lo;
            }
            if (bB) {
                #pragma unroll
                for (int m = 0; m < 2; ++m)
                    #pragma unroll
                    for (int r = 0; r < 16; ++r) {
                        const int keyoff = m * 32 + (r & 3) + ((r >> 2) << 3) + (lh << 2);
                        accs[2 + m][r] += (float)Bnd[wid][lq][pbB + keyoff];
                    }
            } else {
                #pragma unroll
                for (int m = 0; m < 2; ++m)
                    #pragma unroll
                    for (int r = 0; r < 16; ++r) accs[2 + m][r] += qa_hi;
            }
        }

        // online softmax over 128 keys (one update per pair)
        float t8[8];
        #pragma unroll
        for (int i = 0; i < 8; ++i)
            t8[i] = fmaxf(fmaxf(accs[0][i], accs[0][i + 8]),
                          fmaxf(accs[1][i], accs[1][i + 8]));
        #pragma unroll
        for (int i = 0; i < 8; ++i)
            t8[i] = fmaxf(t8[i], fmaxf(fmaxf(accs[2][i], accs[2][i + 8]),
                                       fmaxf(accs[3][i], accs[3][i + 8])));
        float tmax = fmaxf(fmaxf(fmaxf(t8[0], t8[1]), fmaxf(t8[2], t8[3])),
                           fmaxf(fmaxf(t8[4], t8[5]), fmaxf(t8[6], t8[7])));
        tmax = fmaxf(tmax, __shfl_xor(tmax, 32));
        const float mnew = fmaxf(rm, tmax + bunif);
        const bool resc = __any(mnew > rm);
        const float corr = __expf(rm - mnew);
        const float shift = mnew - bunif;
        rm = mnew;

        #pragma unroll
        for (int s = 0; s < 4; ++s)
            #pragma unroll
            for (int r = 0; r < 16; ++r)
                accs[s][r] = __expf(accs[s][r] - shift);

        float s8[8];
        #pragma unroll
        for (int i = 0; i < 8; ++i)
            s8[i] = ((accs[0][i] + accs[0][i + 8]) + (accs[1][i] + accs[1][i + 8]))
                  + ((accs[2][i] + accs[2][i + 8]) + (accs[3][i] + accs[3][i + 8]));
        float psum = ((s8[0] + s8[1]) + (s8[2] + s8[3])) +
                     ((s8[4] + s8[5]) + (s8[6] + s8[7]));
        psum += __shfl_xor(psum, 32);

        if (resc) {
            rl = rl * corr + psum;
            #pragma unroll
            for (int n = 0; n < 2; ++n)
                #pragma unroll
                for (int r = 0; r < 16; ++r) acco[n][r] *= corr;
        } else {
            rl += psum;
        }

        // pack P -> PV B-fragments (A: accs[0..1], B: accs[2..3])
        half8 pfA[4], pfB[4];
        #pragma unroll
        for (int kc = 0; kc < 4; ++kc) {
            {
                const int m = kc >> 1, rb = (kc & 1) * 8;
                unsigned int a01 = PKRTZ(accs[m][rb + 0], accs[m][rb + 1]);
                unsigned int a45 = PKRTZ(accs[m][rb + 4], accs[m][rb + 5]);
                unsigned int a23 = PKRTZ(accs[m][rb + 2], accs[m][rb + 3]);
                unsigned int a67 = PKRTZ(accs[m][rb + 6], accs[m][rb + 7]);
                uint2v r02 = __builtin_amdgcn_permlane32_swap(a01, a45, false, false);
                uint2v r13 = __builtin_amdgcn_permlane32_swap(a23, a67, false, false);
                uint4v wv;
                wv[0] = r02[0]; wv[1] = r13[0]; wv[2] = r02[1]; wv[3] = r13[1];
                pfA[kc] = __builtin_bit_cast(half8, wv);
            }
            {
                const int m = 2 + (kc >> 1), rb = (kc & 1) * 8;
                unsigned int a01 = PKRTZ(accs[m][rb + 0], accs[m][rb + 1]);
                unsigned int a45 = PKRTZ(accs[m][rb + 4], accs[m][rb + 5]);
                unsigned int a23 = PKRTZ(accs[m][rb + 2], accs[m][rb + 3]);
                unsigned int a67 = PKRTZ(accs[m][rb + 6], accs[m][rb + 7]);
                uint2v r02 = __builtin_amdgcn_permlane32_swap(a01, a45, false, false);
                uint2v r13 = __builtin_amdgcn_permlane32_swap(a23, a67, false, false);
                uint4v wv;
                wv[0] = r02[0]; wv[1] = r13[0]; wv[2] = r02[1]; wv[3] = r13[1];
                pfB[kc] = __builtin_bit_cast(half8, wv);
            }
        }

        // O^T += V_A . P_A^T + V_B . P_B^T  (16 MFMA)
        __builtin_amdgcn_s_setprio(1);
        #pragma unroll
        for (int kc = 0; kc < 4; ++kc) {
            half8 v0 = *(const half8*)&Vlds[0][lq][kc * 16 + lh * 8];
            half8 v1 = *(const half8*)&Vlds[0][32 + lq][kc * 16 + lh * 8];
            acco[0] = MFMA(v0, pfA[kc], acco[0]);
            acco[1] = MFMA(v1, pfA[kc], acco[1]);
        }
        #pragma unroll
        for (int kc = 0; kc < 4; ++kc) {
            half8 v0 = *(const half8*)&Vlds[1][lq][kc * 16 + lh * 8];
            half8 v1 = *(const half8*)&Vlds[1][32 + lq][kc * 16 + lh * 8];
            acco[0] = MFMA(v0, pfB[kc], acco[0]);
            acco[1] = MFMA(v1, pfB[kc], acco[1]);
        }
        __builtin_amdgcn_s_setprio(0);

        // band prefetch for pair p+1
        {
            const int dn = diff + 256;
            bA_n = (p + 1 < NP) && (dn > -191) && (dn < 159);
            bB_n = (p + 1 < NP) && (dn > -255) && (dn < 95);
            if (bA_n || bB_n) {
                const int dFB = bA_n ? dn : dn + 64;
                cw0_n = (dFB + 225) & ~7;
                cw0_n = cw0_n > 336 ? 336 : cw0_n;
                #pragma unroll
                for (int i = 0; i < 11; ++i)
                    breg[i] = *(const half8*)&BndSrc[(size_t)brow * QAE_W + cw0_n + bhalf + i * 8];
            }
        }

        // stage next pair K/V -> LDS, issue loads for pair p+2
        if (p + 1 < NP) {
            __syncthreads();                   // all waves done reading pair p
            *(half8*)&Klds[0][srow][sseg] = kA;
            *(half8*)&Klds[1][srow][sseg] = kB;
            *(half8*)&Vlds[0][srow][sseg] = vA;
            *(half8*)&Vlds[1][srow][sseg] = vB;
            if (p + 2 < NP) {
                const int jn = (p + 2) * 256 + kv0;
                kA = *(const half8*)&Kbase[(size_t)(jn + srow) * 64 + sseg];
                kB = *(const half8*)&Kbase[(size_t)(jn + 64 + srow) * 64 + sseg];
                vA = *(const half8*)&Vbase[jn + sseg];
                vB = *(const half8*)&Vbase[jn + 64 + sseg];
            }
            __syncthreads();                   // pair p+1 K/V ready
        }
    }

    // epilogue
    __syncthreads();
    const int orow = wid * 32 + lq;
    #pragma unroll
    for (int n = 0; n < 2; ++n)
        #pragma unroll
        for (int rq = 0; rq < 4; ++rq) {
            uint2v hv;
            hv[0] = PKRTZ(acco[n][rq * 4 + 0], acco[n][rq * 4 + 1]);
            hv[1] = PKRTZ(acco[n][rq * 4 + 2], acco[n][rq * 4 + 3]);
            *(uint2v*)&Obuf[(size_t)orow * 72 + n * 32 + rq * 8 + lh * 4] = hv;
        }
    if (lh == 0)
        Ml[((size_t)ks * BH_NUM + bh) * S_LEN + qg] = make_float2(rm, rl);
    asm volatile("s_waitcnt lgkmcnt(0)" ::: "memory");
    __builtin_amdgcn_sched_barrier(0);
    const int rrow = wid * 32 + (lane >> 1);
    const int rseg = (lane & 1) * 32;
    _Float16* dst = Po + (((size_t)ks * BH_NUM + bh) * S_LEN + i0 + rrow) * 64 + rseg;
    #pragma unroll
    for (int i = 0; i < 4; ++i)
        *(half8*)&dst[8 * i] = *(const half8*)&Obuf[(size_t)rrow * 72 + rseg + 8 * i];
}

// ---------------------------------------------------------------------------
// merge partials + combine heads
// ---------------------------------------------------------------------------
__global__ __launch_bounds__(256) void merge_kernel(
    const _Float16* __restrict__ Po, const float2* __restrict__ Ml,
    float* __restrict__ out)
{
    const int b = blockIdx.y;
    const int s = blockIdx.x * 32 + (threadIdx.x >> 3);
    const int v0 = (threadIdx.x & 7) * 8;
    float acc[8] = {0, 0, 0, 0, 0, 0, 0, 0};
    #pragma unroll
    for (int h = 0; h < 8; ++h) {
        const int bh = b * 8 + h;
        float m[KSPLIT], l[KSPLIT];
        #pragma unroll
        for (int p = 0; p < KSPLIT; ++p) {
            const float2 v = Ml[((size_t)p * BH_NUM + bh) * S_LEN + s];
            m[p] = v.x; l[p] = v.y;
        }
        float M = fmaxf(m[0], m[1]);
        float L = 0.f, w[KSPLIT];
        #pragma unroll
        for (int p = 0; p < KSPLIT; ++p) { w[p] = __expf(m[p] - M); L += w[p] * l[p]; }
        const float invL = 1.0f / L;
        #pragma unroll
        for (int p = 0; p < KSPLIT; ++p) {
            half8 o = *(const half8*)&Po[(((size_t)p * BH_NUM + bh) * S_LEN + s) * 64 + v0];
            const float wp = w[p] * invL;
            #pragma unroll
            for (int j = 0; j < 8; ++j) acc[j] += wp * (float)o[j];
        }
    }
    float4 o0 = {acc[0], acc[1], acc[2], acc[3]};
    float4 o1 = {acc[4], acc[5], acc[6], acc[7]};
    *(float4*)&out[((size_t)b * S_LEN + s) * 64 + v0] = o0;
    *(float4*)&out[((size_t)b * S_LEN + s) * 64 + v0 + 4] = o1;
}

// ---------------------------------------------------------------------------
extern "C" void kernel_launch(void* const* d_in, const int* in_sizes, int n_in,
                              void* d_out, int out_size, void* d_ws, size_t ws_size,
                              hipStream_t stream)
{
    const float* xs  = (const float*)d_in[0];
    const float* w_q = (const float*)d_in[1];
    const float* w_k = (const float*)d_in[2];
    const float* w_v = (const float*)d_in[3];
    const float* w_o = (const float*)d_in[4];
    const float* a_k = (const float*)d_in[5];
    float* out = (float*)d_out;

    char* w = (char*)d_ws;
    _Float16* Xh  = (_Float16*)w;  w += (size_t)B_NUM * S_LEN * E_DIM * 2;        // 4 MB
    _Float16* Wht = (_Float16*)w;  w += (size_t)3 * H_NUM * 64 * 512 * 2;         // 1.5 MB
    _Float16* akh = (_Float16*)w;  w += 33024;
    _Float16* Qh  = (_Float16*)w;  w += (size_t)BH_NUM * S_LEN * 64 * 2;
    _Float16* Kh  = (_Float16*)w;  w += (size_t)BH_NUM * S_LEN * 64 * 2;
    _Float16* Vt  = (_Float16*)w;  w += (size_t)BH_NUM * S_LEN * 64 * 2;
    _Float16* QAe = (_Float16*)w;  w += (size_t)BH_NUM * S_LEN * QAE_W * 2 + 1024; // 33.5 MB + slack
    _Float16* Po  = (_Float16*)w;  w += (size_t)KSPLIT * BH_NUM * S_LEN * 64 * 2;  // 8.4 MB
    float2*   Ml  = (float2*)w;                                                    // 0.5 MB

    cast_x_kernel<<<1024, 256, 0, stream>>>(xs, Xh);
    cast_wak_kernel<<<dim3(8, 8, 4), 256, 0, stream>>>(w_q, w_k, w_v, w_o, a_k, Wht, akh);
    proj_mfma_kernel<<<dim3(16, 16, 3), 256, 0, stream>>>(Xh, Wht, akh, Qh, Kh, Vt, QAe);
    attn_kernel<<<256, 512, 0, stream>>>(Qh, Kh, Vt, QAe, Po, Ml);
    merge_kernel<<<dim3(64, 2), 256, 0, stream>>>(Po, Ml, out);
}